// Round 1
// baseline (567.812 us; speedup 1.0000x reference)
//
#include <hip/hip_runtime.h>

#define WSZ 11
#define HALO 10
#define TILE 32
#define IN_T (TILE + HALO)   // 42
#define NIMG 48              // 16 batch * 3 channels

// ---------------------------------------------------------------------------
// Zero the accumulator area (ws is re-poisoned to 0xAA before every launch).
__global__ void acc_init_kernel(double* acc) {
    if (threadIdx.x < 16) acc[threadIdx.x] = 0.0;
}

// ---------------------------------------------------------------------------
// Fused separable 11x11 Gaussian conv + SSIM map + block reduction.
// One block computes a TILE x TILE output tile of one image (blockIdx.z).
__global__ __launch_bounds__(256) void ssim_scale_kernel(
    const float* __restrict__ A, const float* __restrict__ B,
    int H, int W, double* __restrict__ accCs, double* __restrict__ accSsim)
{
    const int OH = H - HALO;
    const int OW = W - HALO;

    __shared__ float sA[IN_T][IN_T + 2];      // 42 x 44 (pad to dodge conflicts)
    __shared__ float sB[IN_T][IN_T + 2];
    __shared__ float hA [IN_T][TILE + 1];     // horizontal conv results, 42 x 33
    __shared__ float hB [IN_T][TILE + 1];
    __shared__ float hAA[IN_T][TILE + 1];
    __shared__ float hBB[IN_T][TILE + 1];
    __shared__ float hAB[IN_T][TILE + 1];

    // Gaussian window (sigma=1.5, normalized) computed in registers.
    float w[WSZ];
    {
        double tmp[WSZ];
        double s = 0.0;
        #pragma unroll
        for (int i = 0; i < WSZ; ++i) {
            double d = (double)(i - 5);
            tmp[i] = exp(-d * d / 4.5);
            s += tmp[i];
        }
        #pragma unroll
        for (int i = 0; i < WSZ; ++i) w[i] = (float)(tmp[i] / s);
    }

    const int tid = threadIdx.x;
    const int gx0 = blockIdx.x * TILE;
    const int gy0 = blockIdx.y * TILE;
    const int z   = blockIdx.z;
    const float* a = A + (size_t)z * H * W;
    const float* b = B + (size_t)z * H * W;

    // ---- stage input tiles (with halo) into LDS -------------------------
    for (int e = tid; e < IN_T * IN_T; e += 256) {
        int r = e / IN_T, c = e % IN_T;
        int iy = gy0 + r, ix = gx0 + c;
        float va = 0.f, vb = 0.f;
        if (iy < H && ix < W) {
            size_t idx = (size_t)iy * W + ix;
            va = a[idx];
            vb = b[idx];
        }
        sA[r][c] = va;
        sB[r][c] = vb;
    }
    __syncthreads();

    // ---- horizontal 1-D conv of 5 quantities ----------------------------
    for (int e = tid; e < IN_T * TILE; e += 256) {
        int r = e / TILE, c = e % TILE;
        float s1 = 0.f, s2 = 0.f, s11 = 0.f, s22 = 0.f, s12 = 0.f;
        #pragma unroll
        for (int j = 0; j < WSZ; ++j) {
            float va = sA[r][c + j];
            float vb = sB[r][c + j];
            float wj = w[j];
            s1  += wj * va;
            s2  += wj * vb;
            s11 += wj * va * va;
            s22 += wj * vb * vb;
            s12 += wj * va * vb;
        }
        hA [r][c] = s1;
        hB [r][c] = s2;
        hAA[r][c] = s11;
        hBB[r][c] = s22;
        hAB[r][c] = s12;
    }
    __syncthreads();

    // ---- vertical 1-D conv + SSIM math ----------------------------------
    const float C1 = 0.01f * 0.01f;   // (0.01*L)^2, L=1
    const float C2 = 0.03f * 0.03f;
    float csSum = 0.f, ssimSum = 0.f;
    for (int e = tid; e < TILE * TILE; e += 256) {
        int oy = e / TILE, ox = e % TILE;
        int gy = gy0 + oy, gx = gx0 + ox;
        if (gy < OH && gx < OW) {
            float mu1 = 0.f, mu2 = 0.f, saa = 0.f, sbb = 0.f, sab = 0.f;
            #pragma unroll
            for (int i = 0; i < WSZ; ++i) {
                float wi = w[i];
                mu1 += wi * hA [oy + i][ox];
                mu2 += wi * hB [oy + i][ox];
                saa += wi * hAA[oy + i][ox];
                sbb += wi * hBB[oy + i][ox];
                sab += wi * hAB[oy + i][ox];
            }
            float s1sq = saa - mu1 * mu1;
            float s2sq = sbb - mu2 * mu2;
            float s12  = sab - mu1 * mu2;
            float denom = s1sq + s2sq + C2;
            float num_cs = 2.f * s12 + C2;
            float csv = num_cs / denom;
            float ssv = (2.f * mu1 * mu2 + C1) * num_cs /
                        ((mu1 * mu1 + mu2 * mu2 + C1) * denom);
            csSum   += csv;
            ssimSum += ssv;
        }
    }

    // ---- reduction: wave shuffle then cross-wave via LDS ----------------
    #pragma unroll
    for (int off = 32; off > 0; off >>= 1) {
        csSum   += __shfl_down(csSum, off, 64);
        ssimSum += __shfl_down(ssimSum, off, 64);
    }
    __syncthreads();                  // safe to reuse sA as scratch now
    float* red = &sA[0][0];
    int wave = tid >> 6, lane = tid & 63;
    if (lane == 0) {
        red[wave]     = csSum;
        red[8 + wave] = ssimSum;
    }
    __syncthreads();
    if (tid == 0) {
        float c = 0.f, s = 0.f;
        #pragma unroll
        for (int i = 0; i < 4; ++i) { c += red[i]; s += red[8 + i]; }
        atomicAdd(accCs,   (double)c);
        atomicAdd(accSsim, (double)s);
    }
}

// ---------------------------------------------------------------------------
// 2x2 avg-pool (stride 2, floor) of both images at once.
__global__ void pool2_kernel(const float* __restrict__ inA,
                             const float* __restrict__ inB,
                             float* __restrict__ outA,
                             float* __restrict__ outB,
                             int H, int W, int total)   // total = NIMG*(H/2)*(W/2)
{
    const int OH = H >> 1, OW = W >> 1;
    for (int i = blockIdx.x * blockDim.x + threadIdx.x; i < total;
         i += gridDim.x * blockDim.x) {
        int img = i / (OH * OW);
        int rem = i - img * (OH * OW);
        int oy = rem / OW, ox = rem - oy * OW;
        size_t base = (size_t)img * H * W + (size_t)(oy * 2) * W + ox * 2;
        float va = inA[base] + inA[base + 1] + inA[base + W] + inA[base + W + 1];
        float vb = inB[base] + inB[base + 1] + inB[base + W] + inB[base + W + 1];
        outA[i] = 0.25f * va;
        outB[i] = 0.25f * vb;
    }
}

// ---------------------------------------------------------------------------
// Final combine: means, relu, (x+1)/2, weighted geometric product.
__global__ void final_kernel(const double* __restrict__ acc, float* __restrict__ out) {
    if (threadIdx.x == 0 && blockIdx.x == 0) {
        const double wgt[5] = {0.0448, 0.2856, 0.3001, 0.2363, 0.1333};
        double ms = 1.0;
        for (int s = 0; s < 5; ++s) {
            int Hs = 512 >> s;
            double cnt = (double)NIMG * (double)(Hs - 10) * (double)(Hs - 10);
            double cs = acc[s] / cnt;
            double sv = acc[5 + s] / cnt;
            if (cs < 0.0) cs = 0.0;
            if (sv < 0.0) sv = 0.0;
            cs = (cs + 1.0) * 0.5;
            sv = (sv + 1.0) * 0.5;
            ms *= pow((s < 4) ? cs : sv, wgt[s]);
        }
        out[0] = (float)(1.0 - ms);
    }
}

// ---------------------------------------------------------------------------
extern "C" void kernel_launch(void* const* d_in, const int* in_sizes, int n_in,
                              void* d_out, int out_size, void* d_ws, size_t ws_size,
                              hipStream_t stream) {
    (void)in_sizes; (void)n_in; (void)out_size; (void)ws_size;
    const float* A0 = (const float*)d_in[0];
    const float* B0 = (const float*)d_in[1];
    float* out = (float*)d_out;

    char* ws = (char*)d_ws;
    double* acc = (double*)ws;                 // 16 doubles
    float* pyr = (float*)(ws + 256);

    // pyramid buffers for scales 1..4 (A and B)
    float* pa[5] = {nullptr, nullptr, nullptr, nullptr, nullptr};
    float* pb[5] = {nullptr, nullptr, nullptr, nullptr, nullptr};
    size_t off = 0;
    for (int s = 1; s <= 4; ++s) {
        int Hs = 512 >> s;
        size_t n = (size_t)NIMG * Hs * Hs;
        pa[s] = pyr + off; off += n;
        pb[s] = pyr + off; off += n;
    }

    acc_init_kernel<<<1, 64, 0, stream>>>(acc);

    const float* curA = A0;
    const float* curB = B0;
    for (int s = 0; s < 5; ++s) {
        int Hs = 512 >> s;
        int O = Hs - HALO;
        dim3 grid((O + TILE - 1) / TILE, (O + TILE - 1) / TILE, NIMG);
        ssim_scale_kernel<<<grid, 256, 0, stream>>>(curA, curB, Hs, Hs,
                                                    acc + s, acc + 5 + s);
        if (s < 4) {
            int OHs = Hs >> 1;
            int total = NIMG * OHs * OHs;
            int blocks = (total + 255) / 256;
            if (blocks > 16384) blocks = 16384;
            pool2_kernel<<<blocks, 256, 0, stream>>>(curA, curB, pa[s + 1], pb[s + 1],
                                                     Hs, Hs, total);
            curA = pa[s + 1];
            curB = pb[s + 1];
        }
    }

    final_kernel<<<1, 64, 0, stream>>>(acc, out);
}

// Round 2
// 554.366 us; speedup vs baseline: 1.0243x; 1.0243x over previous
//
#include <hip/hip_runtime.h>

#define WSZ 11
#define HALO 10
#define NIMG 48              // 16 batch * 3 channels

// ---------------------------------------------------------------------------
__global__ void acc_init_kernel(double* acc) {
    if (threadIdx.x < 16) acc[threadIdx.x] = 0.0;
}

// ---------------------------------------------------------------------------
// Fused separable 11x11 Gaussian conv + SSIM map + block reduction.
// Output tile: 32 cols x TH rows. Horizontal pass -> LDS (5 quantities),
// vertical pass in registers (4-row strips, sliding window).
template <int TH>
__global__ __launch_bounds__(256) void ssim_scale_kernel(
    const float* __restrict__ A, const float* __restrict__ B,
    int H, int W, double* __restrict__ accCs, double* __restrict__ accSsim)
{
    constexpr int ROWS = TH + HALO;      // input rows needed
    constexpr int SSTR = 44;             // sA/sB row stride (floats, mult of 4)
    constexpr int HSTR = 36;             // h row stride (floats, mult of 4)
    constexpr int SA_OFF = 0;
    constexpr int SB_OFF = ROWS * SSTR;
    constexpr int H_OFF  = 2 * ROWS * SSTR;
    constexpr int HQ     = ROWS * HSTR;  // per-quantity h plane
    constexpr int NF     = H_OFF + 5 * HQ;

    __shared__ __align__(16) float lds[NF];

    // Gaussian window (sigma=1.5, normalized)
    float w[WSZ];
    {
        float tmp[WSZ]; float s = 0.f;
        #pragma unroll
        for (int i = 0; i < WSZ; ++i) {
            float d = (float)(i - 5);
            tmp[i] = __expf(-d * d / 4.5f);
            s += tmp[i];
        }
        float inv = 1.f / s;
        #pragma unroll
        for (int i = 0; i < WSZ; ++i) w[i] = tmp[i] * inv;
    }

    const int tid = threadIdx.x;
    const int gx0 = blockIdx.x * 32;
    const int gy0 = blockIdx.y * TH;
    const size_t ibase = (size_t)blockIdx.z * H * W;
    const float* a = A + ibase;
    const float* b = B + ibase;

    // ---- stage A,B tiles into LDS (float4 granularity, 11 float4/row) ---
    const bool fast = (gy0 + ROWS <= H) && (gx0 + SSTR <= W);
    if (fast) {
        for (int e = tid; e < ROWS * 11; e += 256) {
            int r = e / 11, q = e - r * 11;
            size_t rowoff = (size_t)(gy0 + r) * W + gx0 + q * 4;
            float4 va = *(const float4*)(a + rowoff);
            float4 vb = *(const float4*)(b + rowoff);
            *(float4*)&lds[SA_OFF + r * SSTR + q * 4] = va;
            *(float4*)&lds[SB_OFF + r * SSTR + q * 4] = vb;
        }
    } else {
        for (int e = tid; e < ROWS * 11; e += 256) {
            int r = e / 11, q = e - r * 11;
            int iy = gy0 + r;
            float va[4], vb[4];
            #pragma unroll
            for (int k = 0; k < 4; ++k) {
                int ix = gx0 + q * 4 + k;
                bool ok = (iy < H) && (ix < W);
                size_t idx = (size_t)iy * W + ix;
                va[k] = ok ? a[idx] : 0.f;
                vb[k] = ok ? b[idx] : 0.f;
            }
            *(float4*)&lds[SA_OFF + r * SSTR + q * 4] = make_float4(va[0], va[1], va[2], va[3]);
            *(float4*)&lds[SB_OFF + r * SSTR + q * 4] = make_float4(vb[0], vb[1], vb[2], vb[3]);
        }
    }
    __syncthreads();

    // ---- horizontal conv: 4-col strips, float4 LDS I/O ------------------
    for (int e = tid; e < ROWS * 8; e += 256) {
        int r = e >> 3, c0 = (e & 7) * 4;
        const float* pa = &lds[SA_OFF + r * SSTR + c0];
        const float* pb = &lds[SB_OFF + r * SSTR + c0];
        float fa[16], fb[16];
        #pragma unroll
        for (int v = 0; v < 4; ++v) {
            float4 t = *(const float4*)(pa + v * 4);
            fa[v*4+0] = t.x; fa[v*4+1] = t.y; fa[v*4+2] = t.z; fa[v*4+3] = t.w;
            float4 u = *(const float4*)(pb + v * 4);
            fb[v*4+0] = u.x; fb[v*4+1] = u.y; fb[v*4+2] = u.z; fb[v*4+3] = u.w;
        }
        float s1[4], s2[4], s11[4], s22[4], s12[4];
        #pragma unroll
        for (int k = 0; k < 4; ++k) { s1[k]=0.f; s2[k]=0.f; s11[k]=0.f; s22[k]=0.f; s12[k]=0.f; }
        #pragma unroll
        for (int j = 0; j < WSZ; ++j) {
            float wj = w[j];
            #pragma unroll
            for (int k = 0; k < 4; ++k) {
                float va = fa[k + j], vb = fb[k + j];
                s1[k]  += wj * va;
                s2[k]  += wj * vb;
                s11[k] += wj * va * va;
                s22[k] += wj * vb * vb;
                s12[k] += wj * va * vb;
            }
        }
        int hbase = H_OFF + r * HSTR + c0;
        *(float4*)&lds[hbase + 0*HQ] = make_float4(s1[0],  s1[1],  s1[2],  s1[3]);
        *(float4*)&lds[hbase + 1*HQ] = make_float4(s2[0],  s2[1],  s2[2],  s2[3]);
        *(float4*)&lds[hbase + 2*HQ] = make_float4(s11[0], s11[1], s11[2], s11[3]);
        *(float4*)&lds[hbase + 3*HQ] = make_float4(s22[0], s22[1], s22[2], s22[3]);
        *(float4*)&lds[hbase + 4*HQ] = make_float4(s12[0], s12[1], s12[2], s12[3]);
    }
    __syncthreads();

    // ---- vertical conv (4-row strips, sliding window) + SSIM ------------
    const float C1 = 1e-4f;   // (0.01*1)^2
    const float C2 = 9e-4f;   // (0.03*1)^2
    float csSum = 0.f, ssimSum = 0.f;
    {
        int ox = tid & 31;
        int g  = tid >> 5;
        if (g < TH / 4) {
            int oy0 = g * 4;
            float m[5][4];
            #pragma unroll
            for (int q = 0; q < 5; ++q) {
                const float* hq = &lds[H_OFF + q * HQ + oy0 * HSTR + ox];
                float win[14];
                #pragma unroll
                for (int i = 0; i < 14; ++i) win[i] = hq[i * HSTR];
                #pragma unroll
                for (int k = 0; k < 4; ++k) {
                    float acc = 0.f;
                    #pragma unroll
                    for (int j = 0; j < WSZ; ++j) acc += w[j] * win[k + j];
                    m[q][k] = acc;
                }
            }
            int gx = gx0 + ox;
            const int OH = H - HALO, OW = W - HALO;
            #pragma unroll
            for (int k = 0; k < 4; ++k) {
                int gy = gy0 + oy0 + k;
                if (gy < OH && gx < OW) {
                    float mu1 = m[0][k], mu2 = m[1][k];
                    float saa = m[2][k], sbb = m[3][k], sab = m[4][k];
                    float s1sq = saa - mu1 * mu1;
                    float s2sq = sbb - mu2 * mu2;
                    float s12  = sab - mu1 * mu2;
                    float denom  = s1sq + s2sq + C2;
                    float num_cs = 2.f * s12 + C2;
                    float csv = num_cs * __frcp_rn(denom);
                    float ssv = csv * (2.f * mu1 * mu2 + C1) *
                                __frcp_rn(mu1 * mu1 + mu2 * mu2 + C1);
                    csSum   += csv;
                    ssimSum += ssv;
                }
            }
        }
    }

    // ---- reduction: wave shuffle, then cross-wave via LDS ---------------
    #pragma unroll
    for (int off = 32; off > 0; off >>= 1) {
        csSum   += __shfl_down(csSum, off, 64);
        ssimSum += __shfl_down(ssimSum, off, 64);
    }
    float* red = &lds[0];   // sA region — free after phase-1 barrier
    int wave = tid >> 6, lane = tid & 63;
    if (lane == 0) {
        red[wave]     = csSum;
        red[8 + wave] = ssimSum;
    }
    __syncthreads();
    if (tid == 0) {
        float c = 0.f, s = 0.f;
        #pragma unroll
        for (int i = 0; i < 4; ++i) { c += red[i]; s += red[8 + i]; }
        atomicAdd(accCs,   (double)c);
        atomicAdd(accSsim, (double)s);
    }
}

// ---------------------------------------------------------------------------
// 2x2 avg-pool (stride 2, floor) of both images, float4-vectorized.
__global__ void pool2_kernel(const float* __restrict__ inA,
                             const float* __restrict__ inB,
                             float* __restrict__ outA,
                             float* __restrict__ outB,
                             int H, int W, int total4)  // total4 = NIMG*OH*OW/4
{
    const int OH = H >> 1, OW = W >> 1;
    const int OW4 = OW >> 2;
    for (int i = blockIdx.x * blockDim.x + threadIdx.x; i < total4;
         i += gridDim.x * blockDim.x) {
        int img = i / (OH * OW4);
        int rem = i - img * (OH * OW4);
        int oy = rem / OW4, ox4 = rem - oy * OW4;
        size_t base = (size_t)img * H * W + (size_t)(oy * 2) * W + ox4 * 8;
        float4 a0 = *(const float4*)(inA + base);
        float4 a1 = *(const float4*)(inA + base + 4);
        float4 a2 = *(const float4*)(inA + base + W);
        float4 a3 = *(const float4*)(inA + base + W + 4);
        float4 b0 = *(const float4*)(inB + base);
        float4 b1 = *(const float4*)(inB + base + 4);
        float4 b2 = *(const float4*)(inB + base + W);
        float4 b3 = *(const float4*)(inB + base + W + 4);
        float4 oa, ob;
        oa.x = 0.25f * (a0.x + a0.y + a2.x + a2.y);
        oa.y = 0.25f * (a0.z + a0.w + a2.z + a2.w);
        oa.z = 0.25f * (a1.x + a1.y + a3.x + a3.y);
        oa.w = 0.25f * (a1.z + a1.w + a3.z + a3.w);
        ob.x = 0.25f * (b0.x + b0.y + b2.x + b2.y);
        ob.y = 0.25f * (b0.z + b0.w + b2.z + b2.w);
        ob.z = 0.25f * (b1.x + b1.y + b3.x + b3.y);
        ob.w = 0.25f * (b1.z + b1.w + b3.z + b3.w);
        size_t obase = (size_t)img * OH * OW + (size_t)oy * OW + ox4 * 4;
        *(float4*)(outA + obase) = oa;
        *(float4*)(outB + obase) = ob;
    }
}

// ---------------------------------------------------------------------------
__global__ void final_kernel(const double* __restrict__ acc, float* __restrict__ out) {
    if (threadIdx.x == 0 && blockIdx.x == 0) {
        const double wgt[5] = {0.0448, 0.2856, 0.3001, 0.2363, 0.1333};
        double ms = 1.0;
        for (int s = 0; s < 5; ++s) {
            int Hs = 512 >> s;
            double cnt = (double)NIMG * (double)(Hs - 10) * (double)(Hs - 10);
            double cs = acc[s] / cnt;
            double sv = acc[5 + s] / cnt;
            if (cs < 0.0) cs = 0.0;
            if (sv < 0.0) sv = 0.0;
            cs = (cs + 1.0) * 0.5;
            sv = (sv + 1.0) * 0.5;
            ms *= pow((s < 4) ? cs : sv, wgt[s]);
        }
        out[0] = (float)(1.0 - ms);
    }
}

// ---------------------------------------------------------------------------
extern "C" void kernel_launch(void* const* d_in, const int* in_sizes, int n_in,
                              void* d_out, int out_size, void* d_ws, size_t ws_size,
                              hipStream_t stream) {
    (void)in_sizes; (void)n_in; (void)out_size; (void)ws_size;
    const float* A0 = (const float*)d_in[0];
    const float* B0 = (const float*)d_in[1];
    float* out = (float*)d_out;

    char* ws = (char*)d_ws;
    double* acc = (double*)ws;                 // 16 doubles
    float* pyr = (float*)(ws + 256);

    float* pa[5] = {nullptr, nullptr, nullptr, nullptr, nullptr};
    float* pb[5] = {nullptr, nullptr, nullptr, nullptr, nullptr};
    size_t off = 0;
    for (int s = 1; s <= 4; ++s) {
        int Hs = 512 >> s;
        size_t n = (size_t)NIMG * Hs * Hs;
        pa[s] = pyr + off; off += n;
        pb[s] = pyr + off; off += n;
    }

    acc_init_kernel<<<1, 64, 0, stream>>>(acc);

    const float* curA = A0;
    const float* curB = B0;
    for (int s = 0; s < 5; ++s) {
        int Hs = 512 >> s;
        int O = Hs - HALO;
        if (s <= 2) {
            dim3 grid((O + 31) / 32, (O + 31) / 32, NIMG);
            ssim_scale_kernel<32><<<grid, 256, 0, stream>>>(curA, curB, Hs, Hs,
                                                            acc + s, acc + 5 + s);
        } else if (s == 3) {
            dim3 grid((O + 31) / 32, (O + 15) / 16, NIMG);
            ssim_scale_kernel<16><<<grid, 256, 0, stream>>>(curA, curB, Hs, Hs,
                                                            acc + s, acc + 5 + s);
        } else {
            dim3 grid((O + 31) / 32, (O + 7) / 8, NIMG);
            ssim_scale_kernel<8><<<grid, 256, 0, stream>>>(curA, curB, Hs, Hs,
                                                           acc + s, acc + 5 + s);
        }
        if (s < 4) {
            int OHs = Hs >> 1;
            int total4 = NIMG * OHs * (OHs >> 2);
            int blocks = (total4 + 255) / 256;
            if (blocks > 8192) blocks = 8192;
            pool2_kernel<<<blocks, 256, 0, stream>>>(curA, curB, pa[s + 1], pb[s + 1],
                                                     Hs, Hs, total4);
            curA = pa[s + 1];
            curB = pb[s + 1];
        }
    }

    final_kernel<<<1, 64, 0, stream>>>(acc, out);
}

// Round 3
// 534.247 us; speedup vs baseline: 1.0628x; 1.0377x over previous
//
#include <hip/hip_runtime.h>

#define WSZ  11
#define HALO 10
#define TH   32
#define ROWS (TH + HALO)      // 42 input rows per tile
#define HSTR 36               // h-plane row stride (floats)
#define HQ   (ROWS * HSTR)    // per-quantity plane = 1512 floats
#define NIMG 48               // 16 batch * 3 channels

// Gaussian(sigma=1.5, 11 taps), normalized; computed offline in double.
#define GW { 0.0010284f, 0.0075987f, 0.0360008f, 0.1093607f, 0.2130056f, \
             0.2660117f, 0.2130056f, 0.1093607f, 0.0360008f, 0.0075987f, 0.0010284f }

// ---------------------------------------------------------------------------
__global__ void acc_init_kernel(double* acc) {
    if (threadIdx.x < 16) acc[threadIdx.x] = 0.0;
}

// ---------------------------------------------------------------------------
// Fused: global->reg load + horizontal conv -> LDS h-planes -> vertical conv
// + SSIM + block reduction (+ optional fused 2x2 avg-pool of own region).
// Tile: 32x32 outputs. Grid (x=y=H/32 when FUSE) exactly tiles the image.
template <bool FUSE>
__global__ __launch_bounds__(256, 4) void ssim_scale_kernel(
    const float* __restrict__ A, const float* __restrict__ B,
    int H, int W, double* __restrict__ accCs, double* __restrict__ accSsim,
    float* __restrict__ poolA, float* __restrict__ poolB)
{
    __shared__ __align__(16) float lds[5 * HQ];   // 30240 B
    __shared__ float red[16];

    const float w[WSZ] = GW;

    const int tid = threadIdx.x;
    const int gx0 = blockIdx.x * 32;
    const int gy0 = blockIdx.y * TH;
    const int z   = blockIdx.z;
    const float* a = A + (size_t)z * H * W;
    const float* b = B + (size_t)z * H * W;

    // ---- phase A: load strip from global, h-conv 5 quantities -> LDS ----
    const bool fast = (gy0 + ROWS <= H) && (gx0 + 44 <= W);
    for (int e = tid; e < ROWS * 8; e += 256) {
        int r = e >> 3, c0 = (e & 7) * 4;
        float fa[16], fb[16];
        if (fast) {
            const float* pa = a + (size_t)(gy0 + r) * W + gx0 + c0;
            const float* pb = b + (size_t)(gy0 + r) * W + gx0 + c0;
            *(float4*)&fa[0]  = *(const float4*)(pa);
            *(float4*)&fa[4]  = *(const float4*)(pa + 4);
            *(float4*)&fa[8]  = *(const float4*)(pa + 8);
            *(float4*)&fa[12] = *(const float4*)(pa + 12);
            *(float4*)&fb[0]  = *(const float4*)(pb);
            *(float4*)&fb[4]  = *(const float4*)(pb + 4);
            *(float4*)&fb[8]  = *(const float4*)(pb + 8);
            *(float4*)&fb[12] = *(const float4*)(pb + 12);
        } else {
            int gy = gy0 + r;
            #pragma unroll
            for (int k = 0; k < 14; ++k) {
                int gx = gx0 + c0 + k;
                bool ok = (gy < H) && (gx < W);
                size_t idx = (size_t)gy * W + gx;
                fa[k] = ok ? a[idx] : 0.f;
                fb[k] = ok ? b[idx] : 0.f;
            }
            fa[14] = fa[15] = fb[14] = fb[15] = 0.f;
        }
        float s1[4]  = {0.f, 0.f, 0.f, 0.f};
        float s2[4]  = {0.f, 0.f, 0.f, 0.f};
        float s11[4] = {0.f, 0.f, 0.f, 0.f};
        float s22[4] = {0.f, 0.f, 0.f, 0.f};
        float s12[4] = {0.f, 0.f, 0.f, 0.f};
        #pragma unroll
        for (int j = 0; j < WSZ; ++j) {
            float wj = w[j];
            #pragma unroll
            for (int k = 0; k < 4; ++k) {
                float va = fa[k + j], vb = fb[k + j];
                float t  = wj * va;
                float t2 = wj * vb;
                s1[k]  += t;       s11[k] += t * va;
                s2[k]  += t2;      s22[k] += t2 * vb;
                s12[k] += t2 * va;
            }
        }
        int hb = r * HSTR + c0;
        *(float4*)&lds[hb + 0 * HQ] = make_float4(s1[0],  s1[1],  s1[2],  s1[3]);
        *(float4*)&lds[hb + 1 * HQ] = make_float4(s2[0],  s2[1],  s2[2],  s2[3]);
        *(float4*)&lds[hb + 2 * HQ] = make_float4(s11[0], s11[1], s11[2], s11[3]);
        *(float4*)&lds[hb + 3 * HQ] = make_float4(s22[0], s22[1], s22[2], s22[3]);
        *(float4*)&lds[hb + 4 * HQ] = make_float4(s12[0], s12[1], s12[2], s12[3]);
    }
    __syncthreads();

    // ---- phase B: vertical conv (4-row strip/thread) + SSIM -------------
    const float C1 = 1e-4f;    // (0.01*1)^2
    const float C2 = 9e-4f;    // (0.03*1)^2
    float csSum = 0.f, ssimSum = 0.f;
    {
        const int ox  = tid & 31;
        const int oy0 = (tid >> 5) * 4;
        const float* hp = &lds[oy0 * HSTR + ox];
        float m[5][4];
        {   // mu planes together (ILP across 28 independent LDS reads)
            float u[14], v[14];
            #pragma unroll
            for (int i = 0; i < 14; ++i) {
                u[i] = hp[i * HSTR + 0 * HQ];
                v[i] = hp[i * HSTR + 1 * HQ];
            }
            #pragma unroll
            for (int k = 0; k < 4; ++k) {
                float a0 = 0.f, a1 = 0.f;
                #pragma unroll
                for (int j = 0; j < WSZ; ++j) {
                    a0 += w[j] * u[k + j];
                    a1 += w[j] * v[k + j];
                }
                m[0][k] = a0; m[1][k] = a1;
            }
        }
        {   // second-moment planes together
            float u[14], v[14], x[14];
            #pragma unroll
            for (int i = 0; i < 14; ++i) {
                u[i] = hp[i * HSTR + 2 * HQ];
                v[i] = hp[i * HSTR + 3 * HQ];
                x[i] = hp[i * HSTR + 4 * HQ];
            }
            #pragma unroll
            for (int k = 0; k < 4; ++k) {
                float a2 = 0.f, a3 = 0.f, a4 = 0.f;
                #pragma unroll
                for (int j = 0; j < WSZ; ++j) {
                    a2 += w[j] * u[k + j];
                    a3 += w[j] * v[k + j];
                    a4 += w[j] * x[k + j];
                }
                m[2][k] = a2; m[3][k] = a3; m[4][k] = a4;
            }
        }
        const int OH = H - HALO, OW = W - HALO;
        const int gx = gx0 + ox;
        #pragma unroll
        for (int k = 0; k < 4; ++k) {
            int gy = gy0 + oy0 + k;
            if (gy < OH && gx < OW) {
                float mu1 = m[0][k], mu2 = m[1][k];
                float s1sq = m[2][k] - mu1 * mu1;
                float s2sq = m[3][k] - mu2 * mu2;
                float s12  = m[4][k] - mu1 * mu2;
                float denom  = s1sq + s2sq + C2;
                float num_cs = 2.f * s12 + C2;
                float csv = num_cs * __frcp_rn(denom);
                float ssv = csv * (2.f * mu1 * mu2 + C1) *
                            __frcp_rn(mu1 * mu1 + mu2 * mu2 + C1);
                csSum   += csv;
                ssimSum += ssv;
            }
        }
    }

    // ---- block reduction ------------------------------------------------
    #pragma unroll
    for (int off = 32; off > 0; off >>= 1) {
        csSum   += __shfl_down(csSum, off, 64);
        ssimSum += __shfl_down(ssimSum, off, 64);
    }
    int wave = tid >> 6, lane = tid & 63;
    if (lane == 0) {
        red[wave]     = csSum;
        red[8 + wave] = ssimSum;
    }
    __syncthreads();
    if (tid == 0) {
        float c = 0.f, s = 0.f;
        #pragma unroll
        for (int i = 0; i < 4; ++i) { c += red[i]; s += red[8 + i]; }
        atomicAdd(accCs,   (double)c);
        atomicAdd(accSsim, (double)s);
    }

    // ---- fused 2x2 avg-pool of this block's own 32x32 input region ------
    if (FUSE && tid < 128) {
        const int OH2 = H >> 1, OW2 = W >> 1;
        const int img = tid >> 6;            // 0 = A, 1 = B
        const int rem = tid & 63;
        const int pr  = rem >> 2;            // pooled row 0..15
        const int pq  = rem & 3;             // pooled float4-col 0..3
        const float* src = img ? b : a;
        float* dst = (img ? poolB : poolA) + (size_t)z * OH2 * OW2;
        size_t base = (size_t)(gy0 + 2 * pr) * W + gx0 + pq * 8;
        float4 r0 = *(const float4*)(src + base);
        float4 r1 = *(const float4*)(src + base + 4);
        float4 r2 = *(const float4*)(src + base + W);
        float4 r3 = *(const float4*)(src + base + W + 4);
        float4 o;
        o.x = 0.25f * (r0.x + r0.y + r2.x + r2.y);
        o.y = 0.25f * (r0.z + r0.w + r2.z + r2.w);
        o.z = 0.25f * (r1.x + r1.y + r3.x + r3.y);
        o.w = 0.25f * (r1.z + r1.w + r3.z + r3.w);
        *(float4*)(dst + (size_t)((gy0 >> 1) + pr) * OW2 + (gx0 >> 1) + pq * 4) = o;
    }
}

// ---------------------------------------------------------------------------
__global__ void final_kernel(const double* __restrict__ acc, float* __restrict__ out) {
    if (threadIdx.x == 0 && blockIdx.x == 0) {
        const double wgt[5] = {0.0448, 0.2856, 0.3001, 0.2363, 0.1333};
        double ms = 1.0;
        for (int s = 0; s < 5; ++s) {
            int Hs = 512 >> s;
            double cnt = (double)NIMG * (double)(Hs - 10) * (double)(Hs - 10);
            double cs = acc[s] / cnt;
            double sv = acc[5 + s] / cnt;
            if (cs < 0.0) cs = 0.0;
            if (sv < 0.0) sv = 0.0;
            cs = (cs + 1.0) * 0.5;
            sv = (sv + 1.0) * 0.5;
            ms *= pow((s < 4) ? cs : sv, wgt[s]);
        }
        out[0] = (float)(1.0 - ms);
    }
}

// ---------------------------------------------------------------------------
extern "C" void kernel_launch(void* const* d_in, const int* in_sizes, int n_in,
                              void* d_out, int out_size, void* d_ws, size_t ws_size,
                              hipStream_t stream) {
    (void)in_sizes; (void)n_in; (void)out_size; (void)ws_size;
    const float* A0 = (const float*)d_in[0];
    const float* B0 = (const float*)d_in[1];
    float* out = (float*)d_out;

    char* ws = (char*)d_ws;
    double* acc = (double*)ws;                 // 16 doubles
    float* pyr = (float*)(ws + 256);

    float* pa[5] = {nullptr, nullptr, nullptr, nullptr, nullptr};
    float* pb[5] = {nullptr, nullptr, nullptr, nullptr, nullptr};
    size_t off = 0;
    for (int s = 1; s <= 4; ++s) {
        int Hs = 512 >> s;
        size_t n = (size_t)NIMG * Hs * Hs;
        pa[s] = pyr + off; off += n;
        pb[s] = pyr + off; off += n;
    }

    acc_init_kernel<<<1, 64, 0, stream>>>(acc);

    const float* curA = A0;
    const float* curB = B0;
    for (int s = 0; s < 5; ++s) {
        int Hs = 512 >> s;
        int O  = Hs - HALO;
        int g  = (O + 31) / 32;   // == Hs/32 for Hs in {512,256,128,64}
        dim3 grid(g, g, NIMG);
        if (s < 4) {
            ssim_scale_kernel<true><<<grid, 256, 0, stream>>>(
                curA, curB, Hs, Hs, acc + s, acc + 5 + s, pa[s + 1], pb[s + 1]);
            curA = pa[s + 1];
            curB = pb[s + 1];
        } else {
            ssim_scale_kernel<false><<<grid, 256, 0, stream>>>(
                curA, curB, Hs, Hs, acc + s, acc + 5 + s, nullptr, nullptr);
        }
    }

    final_kernel<<<1, 64, 0, stream>>>(acc, out);
}

// Round 4
// 418.259 us; speedup vs baseline: 1.3576x; 1.2773x over previous
//
#include <hip/hip_runtime.h>

#define WSZ  11
#define HALO 10
#define TH   32
#define ROWS (TH + HALO)      // 42 input rows per tile
#define HSTR 32               // h-plane row stride (floats)
#define HQ   (ROWS * HSTR)    // per-quantity plane = 1344 floats
#define NIMG 48               // 16 batch * 3 channels

// Gaussian(sigma=1.5, 11 taps), normalized; computed offline in double.
#define GW { 0.0010284f, 0.0075987f, 0.0360008f, 0.1093607f, 0.2130056f, \
             0.2660117f, 0.2130056f, 0.1093607f, 0.0360008f, 0.0075987f, 0.0010284f }

// ---------------------------------------------------------------------------
// Fused: global->reg load + horizontal conv -> LDS h-planes -> vertical conv
// + SSIM + block reduction -> per-block partial (+ fused 2x2 avg-pool).
template <bool FUSE>
__global__ __launch_bounds__(256, 6) void ssim_scale_kernel(
    const float* __restrict__ A, const float* __restrict__ B,
    int H, int W, float2* __restrict__ partial,
    float* __restrict__ poolA, float* __restrict__ poolB)
{
    __shared__ __align__(16) float lds[5 * HQ];   // 26880 B
    __shared__ float red[16];

    const float w[WSZ] = GW;

    const int tid = threadIdx.x;
    const int gx0 = blockIdx.x * 32;
    const int gy0 = blockIdx.y * TH;
    const int z   = blockIdx.z;
    const float* a = A + (size_t)z * H * W;
    const float* b = B + (size_t)z * H * W;

    // ---- phase A: load strip from global, h-conv 5 quantities -> LDS ----
    const bool fast = (gy0 + ROWS <= H) && (gx0 + 44 <= W);
    for (int e = tid; e < ROWS * 8; e += 256) {
        int r = e >> 3, c0 = (e & 7) * 4;
        float fa[16], fb[16];
        if (fast) {
            const float* pa = a + (size_t)(gy0 + r) * W + gx0 + c0;
            const float* pb = b + (size_t)(gy0 + r) * W + gx0 + c0;
            *(float4*)&fa[0]  = *(const float4*)(pa);
            *(float4*)&fa[4]  = *(const float4*)(pa + 4);
            *(float4*)&fa[8]  = *(const float4*)(pa + 8);
            *(float4*)&fa[12] = *(const float4*)(pa + 12);
            *(float4*)&fb[0]  = *(const float4*)(pb);
            *(float4*)&fb[4]  = *(const float4*)(pb + 4);
            *(float4*)&fb[8]  = *(const float4*)(pb + 8);
            *(float4*)&fb[12] = *(const float4*)(pb + 12);
        } else {
            int gy = gy0 + r;
            #pragma unroll
            for (int k = 0; k < 14; ++k) {
                int gx = gx0 + c0 + k;
                bool ok = (gy < H) && (gx < W);
                size_t idx = (size_t)gy * W + gx;
                fa[k] = ok ? a[idx] : 0.f;
                fb[k] = ok ? b[idx] : 0.f;
            }
            fa[14] = fa[15] = fb[14] = fb[15] = 0.f;
        }
        float s1[4]  = {0.f, 0.f, 0.f, 0.f};
        float s2[4]  = {0.f, 0.f, 0.f, 0.f};
        float s11[4] = {0.f, 0.f, 0.f, 0.f};
        float s22[4] = {0.f, 0.f, 0.f, 0.f};
        float s12[4] = {0.f, 0.f, 0.f, 0.f};
        #pragma unroll
        for (int j = 0; j < WSZ; ++j) {
            float wj = w[j];
            #pragma unroll
            for (int k = 0; k < 4; ++k) {
                float va = fa[k + j], vb = fb[k + j];
                float t  = wj * va;
                float t2 = wj * vb;
                s1[k]  += t;       s11[k] += t * va;
                s2[k]  += t2;      s22[k] += t2 * vb;
                s12[k] += t2 * va;
            }
        }
        int hb = r * HSTR + c0;
        *(float4*)&lds[hb + 0 * HQ] = make_float4(s1[0],  s1[1],  s1[2],  s1[3]);
        *(float4*)&lds[hb + 1 * HQ] = make_float4(s2[0],  s2[1],  s2[2],  s2[3]);
        *(float4*)&lds[hb + 2 * HQ] = make_float4(s11[0], s11[1], s11[2], s11[3]);
        *(float4*)&lds[hb + 3 * HQ] = make_float4(s22[0], s22[1], s22[2], s22[3]);
        *(float4*)&lds[hb + 4 * HQ] = make_float4(s12[0], s12[1], s12[2], s12[3]);
    }
    __syncthreads();

    // ---- phase B: vertical conv (4-row strip/thread) + SSIM -------------
    const float C1 = 1e-4f;    // (0.01*1)^2
    const float C2 = 9e-4f;    // (0.03*1)^2
    float csSum = 0.f, ssimSum = 0.f;
    {
        const int ox  = tid & 31;
        const int oy0 = (tid >> 5) * 4;
        const float* hp = &lds[oy0 * HSTR + ox];
        float m[5][4];
        {
            float u[14], v[14];
            #pragma unroll
            for (int i = 0; i < 14; ++i) {
                u[i] = hp[i * HSTR + 0 * HQ];
                v[i] = hp[i * HSTR + 1 * HQ];
            }
            #pragma unroll
            for (int k = 0; k < 4; ++k) {
                float a0 = 0.f, a1 = 0.f;
                #pragma unroll
                for (int j = 0; j < WSZ; ++j) {
                    a0 += w[j] * u[k + j];
                    a1 += w[j] * v[k + j];
                }
                m[0][k] = a0; m[1][k] = a1;
            }
        }
        {
            float u[14], v[14], x[14];
            #pragma unroll
            for (int i = 0; i < 14; ++i) {
                u[i] = hp[i * HSTR + 2 * HQ];
                v[i] = hp[i * HSTR + 3 * HQ];
                x[i] = hp[i * HSTR + 4 * HQ];
            }
            #pragma unroll
            for (int k = 0; k < 4; ++k) {
                float a2 = 0.f, a3 = 0.f, a4 = 0.f;
                #pragma unroll
                for (int j = 0; j < WSZ; ++j) {
                    a2 += w[j] * u[k + j];
                    a3 += w[j] * v[k + j];
                    a4 += w[j] * x[k + j];
                }
                m[2][k] = a2; m[3][k] = a3; m[4][k] = a4;
            }
        }
        const int OH = H - HALO, OW = W - HALO;
        const int gx = gx0 + ox;
        #pragma unroll
        for (int k = 0; k < 4; ++k) {
            int gy = gy0 + oy0 + k;
            if (gy < OH && gx < OW) {
                float mu1 = m[0][k], mu2 = m[1][k];
                float s1sq = m[2][k] - mu1 * mu1;
                float s2sq = m[3][k] - mu2 * mu2;
                float s12  = m[4][k] - mu1 * mu2;
                float denom  = s1sq + s2sq + C2;
                float num_cs = 2.f * s12 + C2;
                float csv = num_cs * __frcp_rn(denom);
                float ssv = csv * (2.f * mu1 * mu2 + C1) *
                            __frcp_rn(mu1 * mu1 + mu2 * mu2 + C1);
                csSum   += csv;
                ssimSum += ssv;
            }
        }
    }

    // ---- block reduction -> per-block partial slot ----------------------
    #pragma unroll
    for (int off = 32; off > 0; off >>= 1) {
        csSum   += __shfl_down(csSum, off, 64);
        ssimSum += __shfl_down(ssimSum, off, 64);
    }
    int wave = tid >> 6, lane = tid & 63;
    if (lane == 0) {
        red[wave]     = csSum;
        red[8 + wave] = ssimSum;
    }
    __syncthreads();
    if (tid == 0) {
        float c = 0.f, s = 0.f;
        #pragma unroll
        for (int i = 0; i < 4; ++i) { c += red[i]; s += red[8 + i]; }
        int slot = (z * gridDim.y + blockIdx.y) * gridDim.x + blockIdx.x;
        partial[slot] = make_float2(c, s);
    }

    // ---- fused 2x2 avg-pool of this block's own 32x32 input region ------
    if (FUSE && tid < 128) {
        const int OH2 = H >> 1, OW2 = W >> 1;
        const int img = tid >> 6;            // 0 = A, 1 = B
        const int rem = tid & 63;
        const int pr  = rem >> 2;            // pooled row 0..15
        const int pq  = rem & 3;             // pooled float4-col 0..3
        const float* src = img ? b : a;
        float* dst = (img ? poolB : poolA) + (size_t)z * OH2 * OW2;
        size_t base = (size_t)(gy0 + 2 * pr) * W + gx0 + pq * 8;
        float4 r0 = *(const float4*)(src + base);
        float4 r1 = *(const float4*)(src + base + 4);
        float4 r2 = *(const float4*)(src + base + W);
        float4 r3 = *(const float4*)(src + base + W + 4);
        float4 o;
        o.x = 0.25f * (r0.x + r0.y + r2.x + r2.y);
        o.y = 0.25f * (r0.z + r0.w + r2.z + r2.w);
        o.z = 0.25f * (r1.x + r1.y + r3.x + r3.y);
        o.w = 0.25f * (r1.z + r1.w + r3.z + r3.w);
        *(float4*)(dst + (size_t)((gy0 >> 1) + pr) * OW2 + (gx0 >> 1) + pq * 4) = o;
    }
}

// ---------------------------------------------------------------------------
// Reduce all per-block partials (5 segments) and combine.
__global__ void final_kernel(const float2* __restrict__ partial, float* __restrict__ out) {
    __shared__ double red[8];
    __shared__ double resC[5], resS[5];
    const int segs[6] = {0, 12288, 15360, 16128, 16320, 16368};
    const int tid = threadIdx.x;
    for (int s = 0; s < 5; ++s) {
        double c = 0.0, v = 0.0;
        for (int i = segs[s] + tid; i < segs[s + 1]; i += 256) {
            float2 p = partial[i];
            c += (double)p.x;
            v += (double)p.y;
        }
        #pragma unroll
        for (int off = 32; off > 0; off >>= 1) {
            c += __shfl_down(c, off, 64);
            v += __shfl_down(v, off, 64);
        }
        int wave = tid >> 6, lane = tid & 63;
        __syncthreads();
        if (lane == 0) { red[wave] = c; red[4 + wave] = v; }
        __syncthreads();
        if (tid == 0) {
            resC[s] = red[0] + red[1] + red[2] + red[3];
            resS[s] = red[4] + red[5] + red[6] + red[7];
        }
    }
    __syncthreads();
    if (tid == 0) {
        const double wgt[5] = {0.0448, 0.2856, 0.3001, 0.2363, 0.1333};
        double ms = 1.0;
        for (int s = 0; s < 5; ++s) {
            int Hs = 512 >> s;
            double cnt = (double)NIMG * (double)(Hs - 10) * (double)(Hs - 10);
            double cs = resC[s] / cnt;
            double sv = resS[s] / cnt;
            if (cs < 0.0) cs = 0.0;
            if (sv < 0.0) sv = 0.0;
            cs = (cs + 1.0) * 0.5;
            sv = (sv + 1.0) * 0.5;
            ms *= pow((s < 4) ? cs : sv, wgt[s]);
        }
        out[0] = (float)(1.0 - ms);
    }
}

// ---------------------------------------------------------------------------
extern "C" void kernel_launch(void* const* d_in, const int* in_sizes, int n_in,
                              void* d_out, int out_size, void* d_ws, size_t ws_size,
                              hipStream_t stream) {
    (void)in_sizes; (void)n_in; (void)out_size; (void)ws_size;
    const float* A0 = (const float*)d_in[0];
    const float* B0 = (const float*)d_in[1];
    float* out = (float*)d_out;

    char* ws = (char*)d_ws;
    float2* partial = (float2*)ws;             // 16368 float2 = 131 KB
    float* pyr = (float*)(ws + (1 << 18));     // 256 KB offset

    float* pa[5] = {nullptr, nullptr, nullptr, nullptr, nullptr};
    float* pb[5] = {nullptr, nullptr, nullptr, nullptr, nullptr};
    size_t off = 0;
    for (int s = 1; s <= 4; ++s) {
        int Hs = 512 >> s;
        size_t n = (size_t)NIMG * Hs * Hs;
        pa[s] = pyr + off; off += n;
        pb[s] = pyr + off; off += n;
    }

    const int segs[5] = {0, 12288, 15360, 16128, 16320};

    const float* curA = A0;
    const float* curB = B0;
    for (int s = 0; s < 5; ++s) {
        int Hs = 512 >> s;
        int O  = Hs - HALO;
        int g  = (O + 31) / 32;
        dim3 grid(g, g, NIMG);
        if (s < 4) {
            ssim_scale_kernel<true><<<grid, 256, 0, stream>>>(
                curA, curB, Hs, Hs, partial + segs[s], pa[s + 1], pb[s + 1]);
            curA = pa[s + 1];
            curB = pb[s + 1];
        } else {
            ssim_scale_kernel<false><<<grid, 256, 0, stream>>>(
                curA, curB, Hs, Hs, partial + segs[s], nullptr, nullptr);
        }
    }

    final_kernel<<<1, 256, 0, stream>>>(partial, out);
}

// Round 5
// 319.309 us; speedup vs baseline: 1.7782x; 1.3099x over previous
//
#include <hip/hip_runtime.h>

#define WSZ  11
#define HALO 10
#define TH   32
#define ROWS (TH + HALO)      // 42 input rows per tile
#define HSTR 32               // h-plane row stride (floats)
#define HQ   (ROWS * HSTR)    // per-quantity plane = 1344 floats
#define NIMG 48               // 16 batch * 3 channels

// Gaussian(sigma=1.5, 11 taps), normalized; computed offline in double.
#define GW { 0.0010284f, 0.0075987f, 0.0360008f, 0.1093607f, 0.2130056f, \
             0.2660117f, 0.2130056f, 0.1093607f, 0.0360008f, 0.0075987f, 0.0010284f }

// ---------------------------------------------------------------------------
// Fused: global->reg load + horizontal conv -> LDS h-planes -> vertical conv
// + SSIM + block reduction -> per-block partial (+ fused 2x2 avg-pool).
// launch_bounds(256,5): VGPR budget ~102/wave -- kernel wants ~60, NO spills
// (R4's (256,6) forced 40 VGPR -> 450 MB of scratch spill traffic).
// LDS 27.1 KB -> 6 blocks/CU.
template <bool FUSE>
__global__ __launch_bounds__(256, 5) void ssim_scale_kernel(
    const float* __restrict__ A, const float* __restrict__ B,
    int H, int W, float2* __restrict__ partial,
    float* __restrict__ poolA, float* __restrict__ poolB)
{
    __shared__ __align__(16) float lds[5 * HQ];   // 26880 B
    __shared__ float red[16];

    const float w[WSZ] = GW;

    const int tid = threadIdx.x;
    const int gx0 = blockIdx.x * 32;
    const int gy0 = blockIdx.y * TH;
    const int z   = blockIdx.z;
    const float* a = A + (size_t)z * H * W;
    const float* b = B + (size_t)z * H * W;

    // ---- phase A: load strip from global, h-conv 5 quantities -> LDS ----
    const bool fast = (gy0 + ROWS <= H) && (gx0 + 44 <= W);
    for (int e = tid; e < ROWS * 8; e += 256) {
        int r = e >> 3, c0 = (e & 7) * 4;
        float fa[16], fb[16];
        if (fast) {
            const float* pa = a + (size_t)(gy0 + r) * W + gx0 + c0;
            const float* pb = b + (size_t)(gy0 + r) * W + gx0 + c0;
            *(float4*)&fa[0]  = *(const float4*)(pa);
            *(float4*)&fa[4]  = *(const float4*)(pa + 4);
            *(float4*)&fa[8]  = *(const float4*)(pa + 8);
            *(float4*)&fa[12] = *(const float4*)(pa + 12);
            *(float4*)&fb[0]  = *(const float4*)(pb);
            *(float4*)&fb[4]  = *(const float4*)(pb + 4);
            *(float4*)&fb[8]  = *(const float4*)(pb + 8);
            *(float4*)&fb[12] = *(const float4*)(pb + 12);
        } else {
            int gy = gy0 + r;
            #pragma unroll
            for (int k = 0; k < 14; ++k) {
                int gx = gx0 + c0 + k;
                bool ok = (gy < H) && (gx < W);
                size_t idx = (size_t)gy * W + gx;
                fa[k] = ok ? a[idx] : 0.f;
                fb[k] = ok ? b[idx] : 0.f;
            }
            fa[14] = fa[15] = fb[14] = fb[15] = 0.f;
        }
        float s1[4]  = {0.f, 0.f, 0.f, 0.f};
        float s2[4]  = {0.f, 0.f, 0.f, 0.f};
        float s11[4] = {0.f, 0.f, 0.f, 0.f};
        float s22[4] = {0.f, 0.f, 0.f, 0.f};
        float s12[4] = {0.f, 0.f, 0.f, 0.f};
        #pragma unroll
        for (int j = 0; j < WSZ; ++j) {
            float wj = w[j];
            #pragma unroll
            for (int k = 0; k < 4; ++k) {
                float va = fa[k + j], vb = fb[k + j];
                float t  = wj * va;
                float t2 = wj * vb;
                s1[k]  += t;       s11[k] += t * va;
                s2[k]  += t2;      s22[k] += t2 * vb;
                s12[k] += t2 * va;
            }
        }
        int hb = r * HSTR + c0;
        *(float4*)&lds[hb + 0 * HQ] = make_float4(s1[0],  s1[1],  s1[2],  s1[3]);
        *(float4*)&lds[hb + 1 * HQ] = make_float4(s2[0],  s2[1],  s2[2],  s2[3]);
        *(float4*)&lds[hb + 2 * HQ] = make_float4(s11[0], s11[1], s11[2], s11[3]);
        *(float4*)&lds[hb + 3 * HQ] = make_float4(s22[0], s22[1], s22[2], s22[3]);
        *(float4*)&lds[hb + 4 * HQ] = make_float4(s12[0], s12[1], s12[2], s12[3]);
    }
    __syncthreads();

    // ---- phase B: vertical conv (4-row strip/thread) + SSIM -------------
    const float C1 = 1e-4f;    // (0.01*1)^2
    const float C2 = 9e-4f;    // (0.03*1)^2
    float csSum = 0.f, ssimSum = 0.f;
    {
        const int ox  = tid & 31;
        const int oy0 = (tid >> 5) * 4;
        const float* hp = &lds[oy0 * HSTR + ox];
        float m[5][4];
        {
            float u[14], v[14];
            #pragma unroll
            for (int i = 0; i < 14; ++i) {
                u[i] = hp[i * HSTR + 0 * HQ];
                v[i] = hp[i * HSTR + 1 * HQ];
            }
            #pragma unroll
            for (int k = 0; k < 4; ++k) {
                float a0 = 0.f, a1 = 0.f;
                #pragma unroll
                for (int j = 0; j < WSZ; ++j) {
                    a0 += w[j] * u[k + j];
                    a1 += w[j] * v[k + j];
                }
                m[0][k] = a0; m[1][k] = a1;
            }
        }
        {
            float u[14], v[14], x[14];
            #pragma unroll
            for (int i = 0; i < 14; ++i) {
                u[i] = hp[i * HSTR + 2 * HQ];
                v[i] = hp[i * HSTR + 3 * HQ];
                x[i] = hp[i * HSTR + 4 * HQ];
            }
            #pragma unroll
            for (int k = 0; k < 4; ++k) {
                float a2 = 0.f, a3 = 0.f, a4 = 0.f;
                #pragma unroll
                for (int j = 0; j < WSZ; ++j) {
                    a2 += w[j] * u[k + j];
                    a3 += w[j] * v[k + j];
                    a4 += w[j] * x[k + j];
                }
                m[2][k] = a2; m[3][k] = a3; m[4][k] = a4;
            }
        }
        const int OH = H - HALO, OW = W - HALO;
        const int gx = gx0 + ox;
        #pragma unroll
        for (int k = 0; k < 4; ++k) {
            int gy = gy0 + oy0 + k;
            if (gy < OH && gx < OW) {
                float mu1 = m[0][k], mu2 = m[1][k];
                float s1sq = m[2][k] - mu1 * mu1;
                float s2sq = m[3][k] - mu2 * mu2;
                float s12  = m[4][k] - mu1 * mu2;
                float denom  = s1sq + s2sq + C2;
                float num_cs = 2.f * s12 + C2;
                float csv = num_cs * __frcp_rn(denom);
                float ssv = csv * (2.f * mu1 * mu2 + C1) *
                            __frcp_rn(mu1 * mu1 + mu2 * mu2 + C1);
                csSum   += csv;
                ssimSum += ssv;
            }
        }
    }

    // ---- block reduction -> per-block partial slot ----------------------
    #pragma unroll
    for (int off = 32; off > 0; off >>= 1) {
        csSum   += __shfl_down(csSum, off, 64);
        ssimSum += __shfl_down(ssimSum, off, 64);
    }
    int wave = tid >> 6, lane = tid & 63;
    if (lane == 0) {
        red[wave]     = csSum;
        red[8 + wave] = ssimSum;
    }
    __syncthreads();
    if (tid == 0) {
        float c = 0.f, s = 0.f;
        #pragma unroll
        for (int i = 0; i < 4; ++i) { c += red[i]; s += red[8 + i]; }
        int slot = (z * gridDim.y + blockIdx.y) * gridDim.x + blockIdx.x;
        partial[slot] = make_float2(c, s);
    }

    // ---- fused 2x2 avg-pool of this block's own 32x32 input region ------
    if (FUSE && tid < 128) {
        const int OH2 = H >> 1, OW2 = W >> 1;
        const int img = tid >> 6;            // 0 = A, 1 = B
        const int rem = tid & 63;
        const int pr  = rem >> 2;            // pooled row 0..15
        const int pq  = rem & 3;             // pooled float4-col 0..3
        const float* src = img ? b : a;
        float* dst = (img ? poolB : poolA) + (size_t)z * OH2 * OW2;
        size_t base = (size_t)(gy0 + 2 * pr) * W + gx0 + pq * 8;
        float4 r0 = *(const float4*)(src + base);
        float4 r1 = *(const float4*)(src + base + 4);
        float4 r2 = *(const float4*)(src + base + W);
        float4 r3 = *(const float4*)(src + base + W + 4);
        float4 o;
        o.x = 0.25f * (r0.x + r0.y + r2.x + r2.y);
        o.y = 0.25f * (r0.z + r0.w + r2.z + r2.w);
        o.z = 0.25f * (r1.x + r1.y + r3.x + r3.y);
        o.w = 0.25f * (r1.z + r1.w + r3.z + r3.w);
        *(float4*)(dst + (size_t)((gy0 >> 1) + pr) * OW2 + (gx0 >> 1) + pq * 4) = o;
    }
}

// ---------------------------------------------------------------------------
// Reduce all per-block partials (5 segments) and combine.
__global__ void final_kernel(const float2* __restrict__ partial, float* __restrict__ out) {
    __shared__ double red[8];
    __shared__ double resC[5], resS[5];
    const int segs[6] = {0, 12288, 15360, 16128, 16320, 16368};
    const int tid = threadIdx.x;
    for (int s = 0; s < 5; ++s) {
        double c = 0.0, v = 0.0;
        for (int i = segs[s] + tid; i < segs[s + 1]; i += 256) {
            float2 p = partial[i];
            c += (double)p.x;
            v += (double)p.y;
        }
        #pragma unroll
        for (int off = 32; off > 0; off >>= 1) {
            c += __shfl_down(c, off, 64);
            v += __shfl_down(v, off, 64);
        }
        int wave = tid >> 6, lane = tid & 63;
        __syncthreads();
        if (lane == 0) { red[wave] = c; red[4 + wave] = v; }
        __syncthreads();
        if (tid == 0) {
            resC[s] = red[0] + red[1] + red[2] + red[3];
            resS[s] = red[4] + red[5] + red[6] + red[7];
        }
    }
    __syncthreads();
    if (tid == 0) {
        const double wgt[5] = {0.0448, 0.2856, 0.3001, 0.2363, 0.1333};
        double ms = 1.0;
        for (int s = 0; s < 5; ++s) {
            int Hs = 512 >> s;
            double cnt = (double)NIMG * (double)(Hs - 10) * (double)(Hs - 10);
            double cs = resC[s] / cnt;
            double sv = resS[s] / cnt;
            if (cs < 0.0) cs = 0.0;
            if (sv < 0.0) sv = 0.0;
            cs = (cs + 1.0) * 0.5;
            sv = (sv + 1.0) * 0.5;
            ms *= pow((s < 4) ? cs : sv, wgt[s]);
        }
        out[0] = (float)(1.0 - ms);
    }
}

// ---------------------------------------------------------------------------
extern "C" void kernel_launch(void* const* d_in, const int* in_sizes, int n_in,
                              void* d_out, int out_size, void* d_ws, size_t ws_size,
                              hipStream_t stream) {
    (void)in_sizes; (void)n_in; (void)out_size; (void)ws_size;
    const float* A0 = (const float*)d_in[0];
    const float* B0 = (const float*)d_in[1];
    float* out = (float*)d_out;

    char* ws = (char*)d_ws;
    float2* partial = (float2*)ws;             // 16368 float2 = 131 KB
    float* pyr = (float*)(ws + (1 << 18));     // 256 KB offset

    float* pa[5] = {nullptr, nullptr, nullptr, nullptr, nullptr};
    float* pb[5] = {nullptr, nullptr, nullptr, nullptr, nullptr};
    size_t off = 0;
    for (int s = 1; s <= 4; ++s) {
        int Hs = 512 >> s;
        size_t n = (size_t)NIMG * Hs * Hs;
        pa[s] = pyr + off; off += n;
        pb[s] = pyr + off; off += n;
    }

    const int segs[5] = {0, 12288, 15360, 16128, 16320};

    const float* curA = A0;
    const float* curB = B0;
    for (int s = 0; s < 5; ++s) {
        int Hs = 512 >> s;
        int O  = Hs - HALO;
        int g  = (O + 31) / 32;
        dim3 grid(g, g, NIMG);
        if (s < 4) {
            ssim_scale_kernel<true><<<grid, 256, 0, stream>>>(
                curA, curB, Hs, Hs, partial + segs[s], pa[s + 1], pb[s + 1]);
            curA = pa[s + 1];
            curB = pb[s + 1];
        } else {
            ssim_scale_kernel<false><<<grid, 256, 0, stream>>>(
                curA, curB, Hs, Hs, partial + segs[s], nullptr, nullptr);
        }
    }

    final_kernel<<<1, 256, 0, stream>>>(partial, out);
}

// Round 6
// 279.583 us; speedup vs baseline: 2.0309x; 1.1421x over previous
//
#include <hip/hip_runtime.h>

#define WSZ  11
#define HALO 10
#define TH   32
#define ROWS (TH + HALO)      // 42 input rows per tile
#define HSTR 32               // h-plane row stride (floats)
#define HQ   (ROWS * HSTR)    // per-quantity plane = 1344 floats
#define NIMG 48               // 16 batch * 3 channels

// Gaussian(sigma=1.5, 11 taps), normalized; computed offline in double.
#define GW { 0.0010284f, 0.0075987f, 0.0360008f, 0.1093607f, 0.2130056f, \
             0.2660117f, 0.2130056f, 0.1093607f, 0.0360008f, 0.0075987f, 0.0010284f }

// ---------------------------------------------------------------------------
// Fused: global->reg load + horizontal conv -> LDS h-planes -> vertical conv
// + SSIM + block reduction -> per-block partial (+ fused 2x2 avg-pool).
// Phase A uses incremental chunk accumulation (live-set ~40 regs) and phase B
// per-plane windows (~38 regs) so the (256,5) VGPR budget (48) needs NO spill
// (R4/R5 spilled 450/200 MB to scratch with the array-based structure).
template <bool FUSE>
__global__ __launch_bounds__(256, 5) void ssim_scale_kernel(
    const float* __restrict__ A, const float* __restrict__ B,
    int H, int W, float2* __restrict__ partial,
    float* __restrict__ poolA, float* __restrict__ poolB)
{
    __shared__ __align__(16) float lds[5 * HQ];   // 26880 B
    __shared__ float red[16];

    const float w[WSZ] = GW;

    const int tid = threadIdx.x;
    const int gx0 = blockIdx.x * 32;
    const int gy0 = blockIdx.y * TH;
    const int z   = blockIdx.z;
    const float* a = A + (size_t)z * H * W;
    const float* b = B + (size_t)z * H * W;

    // ---- phase A: load strip from global, h-conv 5 quantities -> LDS ----
    const bool fast = (gy0 + ROWS <= H) && (gx0 + 44 <= W);   // block-uniform
    if (fast) {
        for (int e = tid; e < ROWS * 8; e += 256) {
            int r = e >> 3, c0 = (e & 7) * 4;
            const float* pa = a + (size_t)(gy0 + r) * W + gx0 + c0;
            const float* pb = b + (size_t)(gy0 + r) * W + gx0 + c0;
            float s1[4]  = {0.f, 0.f, 0.f, 0.f};
            float s2[4]  = {0.f, 0.f, 0.f, 0.f};
            float s11[4] = {0.f, 0.f, 0.f, 0.f};
            float s22[4] = {0.f, 0.f, 0.f, 0.f};
            float s12[4] = {0.f, 0.f, 0.f, 0.f};
            float4 ca = *(const float4*)pa;
            float4 cb = *(const float4*)pb;
            #pragma unroll
            for (int c = 0; c < 4; ++c) {
                float4 na, nb;
                if (c < 3) {                      // prefetch next chunk
                    na = *(const float4*)(pa + 4 * (c + 1));
                    nb = *(const float4*)(pb + 4 * (c + 1));
                }
                float ea[4] = {ca.x, ca.y, ca.z, ca.w};
                float eb[4] = {cb.x, cb.y, cb.z, cb.w};
                #pragma unroll
                for (int m = 0; m < 4; ++m) {
                    const int i = 4 * c + m;      // compile-time in unroll
                    float va = ea[m], vb = eb[m];
                    float vaa = va * va, vbb = vb * vb, vab = va * vb;
                    #pragma unroll
                    for (int k = 0; k < 4; ++k) {
                        const int j = i - k;
                        if (j >= 0 && j <= 10) {  // folds at compile time
                            float wj = w[j];
                            s1[k]  += wj * va;
                            s2[k]  += wj * vb;
                            s11[k] += wj * vaa;
                            s22[k] += wj * vbb;
                            s12[k] += wj * vab;
                        }
                    }
                }
                if (c < 3) { ca = na; cb = nb; }
            }
            int hb = r * HSTR + c0;
            *(float4*)&lds[hb + 0 * HQ] = make_float4(s1[0],  s1[1],  s1[2],  s1[3]);
            *(float4*)&lds[hb + 1 * HQ] = make_float4(s2[0],  s2[1],  s2[2],  s2[3]);
            *(float4*)&lds[hb + 2 * HQ] = make_float4(s11[0], s11[1], s11[2], s11[3]);
            *(float4*)&lds[hb + 3 * HQ] = make_float4(s22[0], s22[1], s22[2], s22[3]);
            *(float4*)&lds[hb + 4 * HQ] = make_float4(s12[0], s12[1], s12[2], s12[3]);
        }
    } else {
        for (int e = tid; e < ROWS * 8; e += 256) {
            int r = e >> 3, c0 = (e & 7) * 4;
            int gy = gy0 + r;
            float s1[4]  = {0.f, 0.f, 0.f, 0.f};
            float s2[4]  = {0.f, 0.f, 0.f, 0.f};
            float s11[4] = {0.f, 0.f, 0.f, 0.f};
            float s22[4] = {0.f, 0.f, 0.f, 0.f};
            float s12[4] = {0.f, 0.f, 0.f, 0.f};
            #pragma unroll
            for (int c = 0; c < 4; ++c) {
                float ea[4], eb[4];
                #pragma unroll
                for (int t = 0; t < 4; ++t) {
                    int gx = gx0 + c0 + 4 * c + t;
                    bool ok = (gy < H) && (gx < W);
                    size_t idx = (size_t)gy * W + gx;
                    ea[t] = ok ? a[idx] : 0.f;
                    eb[t] = ok ? b[idx] : 0.f;
                }
                #pragma unroll
                for (int m = 0; m < 4; ++m) {
                    const int i = 4 * c + m;
                    float va = ea[m], vb = eb[m];
                    float vaa = va * va, vbb = vb * vb, vab = va * vb;
                    #pragma unroll
                    for (int k = 0; k < 4; ++k) {
                        const int j = i - k;
                        if (j >= 0 && j <= 10) {
                            float wj = w[j];
                            s1[k]  += wj * va;
                            s2[k]  += wj * vb;
                            s11[k] += wj * vaa;
                            s22[k] += wj * vbb;
                            s12[k] += wj * vab;
                        }
                    }
                }
            }
            int hb = r * HSTR + c0;
            *(float4*)&lds[hb + 0 * HQ] = make_float4(s1[0],  s1[1],  s1[2],  s1[3]);
            *(float4*)&lds[hb + 1 * HQ] = make_float4(s2[0],  s2[1],  s2[2],  s2[3]);
            *(float4*)&lds[hb + 2 * HQ] = make_float4(s11[0], s11[1], s11[2], s11[3]);
            *(float4*)&lds[hb + 3 * HQ] = make_float4(s22[0], s22[1], s22[2], s22[3]);
            *(float4*)&lds[hb + 4 * HQ] = make_float4(s12[0], s12[1], s12[2], s12[3]);
        }
    }
    __syncthreads();

    // ---- phase B: vertical conv (4-row strip/thread, per-plane) + SSIM --
    const float C1 = 1e-4f;    // (0.01*1)^2
    const float C2 = 9e-4f;    // (0.03*1)^2
    float csSum = 0.f, ssimSum = 0.f;
    {
        const int ox  = tid & 31;
        const int oy0 = (tid >> 5) * 4;
        float m[5][4];
        #pragma unroll
        for (int q = 0; q < 5; ++q) {
            const float* hq = &lds[q * HQ + oy0 * HSTR + ox];
            float win[14];
            #pragma unroll
            for (int i = 0; i < 14; ++i) win[i] = hq[i * HSTR];
            #pragma unroll
            for (int k = 0; k < 4; ++k) {
                float acc = 0.f;
                #pragma unroll
                for (int j = 0; j < WSZ; ++j) acc += w[j] * win[k + j];
                m[q][k] = acc;
            }
        }
        const int OH = H - HALO, OW = W - HALO;
        const int gx = gx0 + ox;
        #pragma unroll
        for (int k = 0; k < 4; ++k) {
            int gy = gy0 + oy0 + k;
            if (gy < OH && gx < OW) {
                float mu1 = m[0][k], mu2 = m[1][k];
                float s1sq = m[2][k] - mu1 * mu1;
                float s2sq = m[3][k] - mu2 * mu2;
                float s12  = m[4][k] - mu1 * mu2;
                float denom  = s1sq + s2sq + C2;
                float num_cs = 2.f * s12 + C2;
                float csv = num_cs * __frcp_rn(denom);
                float ssv = csv * (2.f * mu1 * mu2 + C1) *
                            __frcp_rn(mu1 * mu1 + mu2 * mu2 + C1);
                csSum   += csv;
                ssimSum += ssv;
            }
        }
    }

    // ---- block reduction -> per-block partial slot ----------------------
    #pragma unroll
    for (int off = 32; off > 0; off >>= 1) {
        csSum   += __shfl_down(csSum, off, 64);
        ssimSum += __shfl_down(ssimSum, off, 64);
    }
    int wave = tid >> 6, lane = tid & 63;
    if (lane == 0) {
        red[wave]     = csSum;
        red[8 + wave] = ssimSum;
    }
    __syncthreads();
    if (tid == 0) {
        float c = 0.f, s = 0.f;
        #pragma unroll
        for (int i = 0; i < 4; ++i) { c += red[i]; s += red[8 + i]; }
        int slot = (z * gridDim.y + blockIdx.y) * gridDim.x + blockIdx.x;
        partial[slot] = make_float2(c, s);
    }

    // ---- fused 2x2 avg-pool of this block's own 32x32 input region ------
    if (FUSE && tid < 128) {
        const int OH2 = H >> 1, OW2 = W >> 1;
        const int img = tid >> 6;            // 0 = A, 1 = B
        const int rem = tid & 63;
        const int pr  = rem >> 2;            // pooled row 0..15
        const int pq  = rem & 3;             // pooled float4-col 0..3
        const float* src = img ? b : a;
        float* dst = (img ? poolB : poolA) + (size_t)z * OH2 * OW2;
        size_t base = (size_t)(gy0 + 2 * pr) * W + gx0 + pq * 8;
        float4 r0 = *(const float4*)(src + base);
        float4 r1 = *(const float4*)(src + base + 4);
        float4 r2 = *(const float4*)(src + base + W);
        float4 r3 = *(const float4*)(src + base + W + 4);
        float4 o;
        o.x = 0.25f * (r0.x + r0.y + r2.x + r2.y);
        o.y = 0.25f * (r0.z + r0.w + r2.z + r2.w);
        o.z = 0.25f * (r1.x + r1.y + r3.x + r3.y);
        o.w = 0.25f * (r1.z + r1.w + r3.z + r3.w);
        *(float4*)(dst + (size_t)((gy0 >> 1) + pr) * OW2 + (gx0 >> 1) + pq * 4) = o;
    }
}

// ---------------------------------------------------------------------------
// Reduce all per-block partials (5 segments) and combine.
__global__ void final_kernel(const float2* __restrict__ partial, float* __restrict__ out) {
    __shared__ double red[8];
    __shared__ double resC[5], resS[5];
    const int segs[6] = {0, 12288, 15360, 16128, 16320, 16368};
    const int tid = threadIdx.x;
    for (int s = 0; s < 5; ++s) {
        double c = 0.0, v = 0.0;
        for (int i = segs[s] + tid; i < segs[s + 1]; i += 256) {
            float2 p = partial[i];
            c += (double)p.x;
            v += (double)p.y;
        }
        #pragma unroll
        for (int off = 32; off > 0; off >>= 1) {
            c += __shfl_down(c, off, 64);
            v += __shfl_down(v, off, 64);
        }
        int wave = tid >> 6, lane = tid & 63;
        __syncthreads();
        if (lane == 0) { red[wave] = c; red[4 + wave] = v; }
        __syncthreads();
        if (tid == 0) {
            resC[s] = red[0] + red[1] + red[2] + red[3];
            resS[s] = red[4] + red[5] + red[6] + red[7];
        }
    }
    __syncthreads();
    if (tid == 0) {
        const double wgt[5] = {0.0448, 0.2856, 0.3001, 0.2363, 0.1333};
        double ms = 1.0;
        for (int s = 0; s < 5; ++s) {
            int Hs = 512 >> s;
            double cnt = (double)NIMG * (double)(Hs - 10) * (double)(Hs - 10);
            double cs = resC[s] / cnt;
            double sv = resS[s] / cnt;
            if (cs < 0.0) cs = 0.0;
            if (sv < 0.0) sv = 0.0;
            cs = (cs + 1.0) * 0.5;
            sv = (sv + 1.0) * 0.5;
            ms *= pow((s < 4) ? cs : sv, wgt[s]);
        }
        out[0] = (float)(1.0 - ms);
    }
}

// ---------------------------------------------------------------------------
extern "C" void kernel_launch(void* const* d_in, const int* in_sizes, int n_in,
                              void* d_out, int out_size, void* d_ws, size_t ws_size,
                              hipStream_t stream) {
    (void)in_sizes; (void)n_in; (void)out_size; (void)ws_size;
    const float* A0 = (const float*)d_in[0];
    const float* B0 = (const float*)d_in[1];
    float* out = (float*)d_out;

    char* ws = (char*)d_ws;
    float2* partial = (float2*)ws;             // 16368 float2 = 131 KB
    float* pyr = (float*)(ws + (1 << 18));     // 256 KB offset

    float* pa[5] = {nullptr, nullptr, nullptr, nullptr, nullptr};
    float* pb[5] = {nullptr, nullptr, nullptr, nullptr, nullptr};
    size_t off = 0;
    for (int s = 1; s <= 4; ++s) {
        int Hs = 512 >> s;
        size_t n = (size_t)NIMG * Hs * Hs;
        pa[s] = pyr + off; off += n;
        pb[s] = pyr + off; off += n;
    }

    const int segs[5] = {0, 12288, 15360, 16128, 16320};

    const float* curA = A0;
    const float* curB = B0;
    for (int s = 0; s < 5; ++s) {
        int Hs = 512 >> s;
        int O  = Hs - HALO;
        int g  = (O + 31) / 32;
        dim3 grid(g, g, NIMG);
        if (s < 4) {
            ssim_scale_kernel<true><<<grid, 256, 0, stream>>>(
                curA, curB, Hs, Hs, partial + segs[s], pa[s + 1], pb[s + 1]);
            curA = pa[s + 1];
            curB = pb[s + 1];
        } else {
            ssim_scale_kernel<false><<<grid, 256, 0, stream>>>(
                curA, curB, Hs, Hs, partial + segs[s], nullptr, nullptr);
        }
    }

    final_kernel<<<1, 256, 0, stream>>>(partial, out);
}

// Round 8
// 242.824 us; speedup vs baseline: 2.3384x; 1.1514x over previous
//
#include <hip/hip_runtime.h>

#define HALO 10
#define NIMG 48                 // 16 batch * 3 channels

// Gaussian(sigma=1.5, 11 taps), normalized (computed offline in double).
#define GWLIST { 0.0010284f, 0.0075987f, 0.0360008f, 0.1093607f, 0.2130056f, \
                 0.2660117f, 0.2130056f, 0.1093607f, 0.0360008f, 0.0075987f, 0.0010284f }

// ======================= MFMA kernel (scales 0,1) ==========================
#define PP   48                 // stage-1 plane pitch (fp16 units), 96 B
#define PSZ  (48 * 48)          // plane size = 2304 fp16
#define HT0  (5 * PSZ)          // h_T base offset = 11520 fp16
#define HTP  48                 // h_T pitch along r (fp16 units)
#define HTSZ (32 * 48)          // per-quantity h_T = 1536 fp16
#define LDSH (HT0 + 5 * HTSZ)   // 19200 fp16 = 38400 B

typedef _Float16 half8 __attribute__((ext_vector_type(8)));
typedef _Float16 half4 __attribute__((ext_vector_type(4)));
typedef float    floatx4 __attribute__((ext_vector_type(4)));

// Per 32x32-output block:
//  stage 1: load 48x48 region, build 5 fp16 quantity planes in LDS
//           (squares/products computed from the fp16-quantized signal so
//            mu and sigma measure the same quantized image)
//  stage 2: h-conv via mfma_f32_16x16x32_f16 (In x W_band), C -> fp16 h_T
//           stored transposed (contiguous b64 writes)
//  stage 3: v-conv via mfma (W_band x h_T), SSIM on C fragments,
//           block reduce -> partial slot (+ fused 2x2 avg-pool).
// Weight band fragment identical in A- and B-layout:
//   val = w[(lane>>4)*8 + i - (lane&15)] (0 outside [0,10]).
// fp16 is ONLY used for scales 0-1 where cs denominators are >=0.04;
// deeper scales have denom ~1e-3 and fp16 sigma errors blow past the
// absmax threshold (R7 failed at 9.8e-3 with all scales fp16).
template <bool FUSE>
__global__ __launch_bounds__(256, 4) void ssim_mfma_kernel(
    const float* __restrict__ A, const float* __restrict__ B,
    int H, int W, float2* __restrict__ partial,
    float* __restrict__ poolA, float* __restrict__ poolB)
{
    __shared__ __align__(16) _Float16 sm[LDSH];   // 38400 B
    __shared__ float red[16];

    const float w[11] = GWLIST;
    const int tid  = threadIdx.x;
    const int lane = tid & 63;
    const int wv   = tid >> 6;
    const int gx0  = blockIdx.x * 32;
    const int gy0  = blockIdx.y * 32;
    const int z    = blockIdx.z;
    const float* a = A + (size_t)z * H * W;
    const float* b = B + (size_t)z * H * W;

    // ---- band-weight fragment -------------------------------------------
    half8 wfrag;
    {
        int base = ((lane >> 4) << 3) - (lane & 15);
        #pragma unroll
        for (int i = 0; i < 8; ++i) {
            int j = base + i;
            float v = 0.f;
            #pragma unroll
            for (int J = 0; J < 11; ++J) v = (j == J) ? w[J] : v;
            wfrag[i] = (_Float16)v;
        }
    }

    // ---- stage 1: 48x48 region -> 5 fp16 quantity planes ----------------
    const bool fast = (gy0 + 48 <= H) && (gx0 + 48 <= W);
    for (int e = tid; e < 288; e += 256) {        // 48 rows x 6 col-octets
        int r = e / 6, c8 = e - r * 6;
        float fa[8], fb[8];
        if (fast) {
            const float* pa = a + (size_t)(gy0 + r) * W + gx0 + c8 * 8;
            const float* pb = b + (size_t)(gy0 + r) * W + gx0 + c8 * 8;
            *(float4*)&fa[0] = *(const float4*)pa;
            *(float4*)&fa[4] = *(const float4*)(pa + 4);
            *(float4*)&fb[0] = *(const float4*)pb;
            *(float4*)&fb[4] = *(const float4*)(pb + 4);
        } else {
            int gy = gy0 + r;
            #pragma unroll
            for (int i = 0; i < 8; ++i) {
                int gx = gx0 + c8 * 8 + i;
                bool ok = (gy < H) && (gx < W);
                size_t idx = (size_t)gy * W + gx;
                fa[i] = ok ? a[idx] : 0.f;
                fb[i] = ok ? b[idx] : 0.f;
            }
        }
        half8 ha, hb, haa, hbb, hab;
        #pragma unroll
        for (int i = 0; i < 8; ++i) {
            ha[i] = (_Float16)fa[i];
            hb[i] = (_Float16)fb[i];
            float qa = (float)ha[i];      // quantized signal
            float qb = (float)hb[i];
            haa[i] = (_Float16)(qa * qa);
            hbb[i] = (_Float16)(qb * qb);
            hab[i] = (_Float16)(qa * qb);
        }
        int o = r * PP + c8 * 8;
        *(half8*)&sm[o + 0 * PSZ] = ha;
        *(half8*)&sm[o + 1 * PSZ] = hb;
        *(half8*)&sm[o + 2 * PSZ] = haa;
        *(half8*)&sm[o + 3 * PSZ] = hbb;
        *(half8*)&sm[o + 4 * PSZ] = hab;
    }
    __syncthreads();

    // ---- stage 2: h-conv via MFMA, write transposed fp16 h_T ------------
    {
        const int arow = (lane & 15) * PP + ((lane >> 4) << 3);
        const int crow = (lane & 15) * HTP + ((lane >> 4) << 2);
        for (int jj = wv; jj < 30; jj += 4) {
            int q = jj / 6, rem = jj - q * 6;
            int m0 = (rem >> 1) << 4;
            int x0 = (rem & 1) << 4;
            half8 afrag = *(const half8*)&sm[q * PSZ + m0 * PP + x0 + arow];
            floatx4 c = {0.f, 0.f, 0.f, 0.f};
            c = __builtin_amdgcn_mfma_f32_16x16x32_f16(afrag, wfrag, c, 0, 0, 0);
            half4 hv;
            hv[0] = (_Float16)c[0]; hv[1] = (_Float16)c[1];
            hv[2] = (_Float16)c[2]; hv[3] = (_Float16)c[3];
            *(half4*)&sm[HT0 + q * HTSZ + x0 * HTP + m0 + crow] = hv;
        }
    }
    __syncthreads();

    // ---- stage 3: v-conv via MFMA (one 16x16 subtile per wave) + SSIM ---
    float csSum = 0.f, ssimSum = 0.f;
    {
        const int y0 = (wv >> 1) << 4;
        const int x0 = (wv & 1) << 4;
        const int brow = (lane & 15) * HTP + ((lane >> 4) << 3);
        floatx4 m[5];
        #pragma unroll
        for (int q = 0; q < 5; ++q) {
            half8 bfrag = *(const half8*)&sm[HT0 + q * HTSZ + x0 * HTP + y0 + brow];
            floatx4 c = {0.f, 0.f, 0.f, 0.f};
            m[q] = __builtin_amdgcn_mfma_f32_16x16x32_f16(wfrag, bfrag, c, 0, 0, 0);
        }
        const int OH = H - HALO, OW = W - HALO;
        const int gx  = gx0 + x0 + (lane & 15);
        const int gyb = gy0 + y0 + ((lane >> 4) << 2);
        const float C1 = 1e-4f;   // (0.01*1)^2
        const float C2 = 9e-4f;   // (0.03*1)^2
        if (gx < OW) {
            #pragma unroll
            for (int i = 0; i < 4; ++i) {
                int gy = gyb + i;
                if (gy < OH) {
                    float mu1 = m[0][i], mu2 = m[1][i];
                    float s1sq = m[2][i] - mu1 * mu1;
                    float s2sq = m[3][i] - mu2 * mu2;
                    float s12  = m[4][i] - mu1 * mu2;
                    float denom = s1sq + s2sq + C2;
                    float num   = 2.f * s12 + C2;
                    float csv = num * __frcp_rn(denom);
                    float ssv = csv * (2.f * mu1 * mu2 + C1) *
                                __frcp_rn(mu1 * mu1 + mu2 * mu2 + C1);
                    csSum   += csv;
                    ssimSum += ssv;
                }
            }
        }
    }

    // ---- block reduction -> per-block partial slot ----------------------
    #pragma unroll
    for (int off = 32; off > 0; off >>= 1) {
        csSum   += __shfl_down(csSum, off, 64);
        ssimSum += __shfl_down(ssimSum, off, 64);
    }
    if (lane == 0) {
        red[wv]     = csSum;
        red[8 + wv] = ssimSum;
    }
    __syncthreads();
    if (tid == 0) {
        float c = 0.f, s = 0.f;
        #pragma unroll
        for (int i = 0; i < 4; ++i) { c += red[i]; s += red[8 + i]; }
        int slot = (z * gridDim.y + blockIdx.y) * gridDim.x + blockIdx.x;
        partial[slot] = make_float2(c, s);
    }

    // ---- fused 2x2 avg-pool of this block's own 32x32 input region ------
    if (FUSE && tid < 128) {
        const int OH2 = H >> 1, OW2 = W >> 1;
        const int img = tid >> 6;            // 0 = A, 1 = B
        const int rem = tid & 63;
        const int pr  = rem >> 2;            // pooled row 0..15
        const int pq  = rem & 3;             // pooled float4-col 0..3
        const float* src = img ? b : a;
        float* dst = (img ? poolB : poolA) + (size_t)z * OH2 * OW2;
        size_t base = (size_t)(gy0 + 2 * pr) * W + gx0 + pq * 8;
        float4 r0 = *(const float4*)(src + base);
        float4 r1 = *(const float4*)(src + base + 4);
        float4 r2 = *(const float4*)(src + base + W);
        float4 r3 = *(const float4*)(src + base + W + 4);
        float4 o;
        o.x = 0.25f * (r0.x + r0.y + r2.x + r2.y);
        o.y = 0.25f * (r0.z + r0.w + r2.z + r2.w);
        o.z = 0.25f * (r1.x + r1.y + r3.x + r3.y);
        o.w = 0.25f * (r1.z + r1.w + r3.z + r3.w);
        *(float4*)(dst + (size_t)((gy0 >> 1) + pr) * OW2 + (gx0 >> 1) + pq * 4) = o;
    }
}

// ================= exact fp32 scalar kernel (scales 2-4) ===================
#define TH   32
#define ROWS (TH + HALO)      // 42
#define HSTR 32
#define HQ   (ROWS * HSTR)    // 1344 floats

template <bool FUSE>
__global__ __launch_bounds__(256, 5) void ssim_scalar_kernel(
    const float* __restrict__ A, const float* __restrict__ B,
    int H, int W, float2* __restrict__ partial,
    float* __restrict__ poolA, float* __restrict__ poolB)
{
    __shared__ __align__(16) float lds[5 * HQ];   // 26880 B
    __shared__ float red[16];

    const float w[11] = GWLIST;

    const int tid = threadIdx.x;
    const int gx0 = blockIdx.x * 32;
    const int gy0 = blockIdx.y * TH;
    const int z   = blockIdx.z;
    const float* a = A + (size_t)z * H * W;
    const float* b = B + (size_t)z * H * W;

    const bool fast = (gy0 + ROWS <= H) && (gx0 + 44 <= W);
    for (int e = tid; e < ROWS * 8; e += 256) {
        int r = e >> 3, c0 = (e & 7) * 4;
        int gy = gy0 + r;
        float s1[4]  = {0.f, 0.f, 0.f, 0.f};
        float s2[4]  = {0.f, 0.f, 0.f, 0.f};
        float s11[4] = {0.f, 0.f, 0.f, 0.f};
        float s22[4] = {0.f, 0.f, 0.f, 0.f};
        float s12[4] = {0.f, 0.f, 0.f, 0.f};
        #pragma unroll
        for (int c = 0; c < 4; ++c) {
            float ea[4], eb[4];
            if (fast) {
                const float* pa = a + (size_t)gy * W + gx0 + c0 + 4 * c;
                const float* pb = b + (size_t)gy * W + gx0 + c0 + 4 * c;
                *(float4*)&ea[0] = *(const float4*)pa;
                *(float4*)&eb[0] = *(const float4*)pb;
            } else {
                #pragma unroll
                for (int t = 0; t < 4; ++t) {
                    int gx = gx0 + c0 + 4 * c + t;
                    bool ok = (gy < H) && (gx < W);
                    size_t idx = (size_t)gy * W + gx;
                    ea[t] = ok ? a[idx] : 0.f;
                    eb[t] = ok ? b[idx] : 0.f;
                }
            }
            #pragma unroll
            for (int mm = 0; mm < 4; ++mm) {
                const int i = 4 * c + mm;
                float va = ea[mm], vb = eb[mm];
                float vaa = va * va, vbb = vb * vb, vab = va * vb;
                #pragma unroll
                for (int k = 0; k < 4; ++k) {
                    const int j = i - k;
                    if (j >= 0 && j <= 10) {
                        float wj = w[j];
                        s1[k]  += wj * va;
                        s2[k]  += wj * vb;
                        s11[k] += wj * vaa;
                        s22[k] += wj * vbb;
                        s12[k] += wj * vab;
                    }
                }
            }
        }
        int hb = r * HSTR + c0;
        *(float4*)&lds[hb + 0 * HQ] = make_float4(s1[0],  s1[1],  s1[2],  s1[3]);
        *(float4*)&lds[hb + 1 * HQ] = make_float4(s2[0],  s2[1],  s2[2],  s2[3]);
        *(float4*)&lds[hb + 2 * HQ] = make_float4(s11[0], s11[1], s11[2], s11[3]);
        *(float4*)&lds[hb + 3 * HQ] = make_float4(s22[0], s22[1], s22[2], s22[3]);
        *(float4*)&lds[hb + 4 * HQ] = make_float4(s12[0], s12[1], s12[2], s12[3]);
    }
    __syncthreads();

    const float C1 = 1e-4f;
    const float C2 = 9e-4f;
    float csSum = 0.f, ssimSum = 0.f;
    {
        const int ox  = tid & 31;
        const int oy0 = (tid >> 5) * 4;
        float m[5][4];
        #pragma unroll
        for (int q = 0; q < 5; ++q) {
            const float* hq = &lds[q * HQ + oy0 * HSTR + ox];
            float win[14];
            #pragma unroll
            for (int i = 0; i < 14; ++i) win[i] = hq[i * HSTR];
            #pragma unroll
            for (int k = 0; k < 4; ++k) {
                float acc = 0.f;
                #pragma unroll
                for (int j = 0; j < 11; ++j) acc += w[j] * win[k + j];
                m[q][k] = acc;
            }
        }
        const int OH = H - HALO, OW = W - HALO;
        const int gx = gx0 + ox;
        #pragma unroll
        for (int k = 0; k < 4; ++k) {
            int gy = gy0 + oy0 + k;
            if (gy < OH && gx < OW) {
                float mu1 = m[0][k], mu2 = m[1][k];
                float s1sq = m[2][k] - mu1 * mu1;
                float s2sq = m[3][k] - mu2 * mu2;
                float s12  = m[4][k] - mu1 * mu2;
                float denom  = s1sq + s2sq + C2;
                float num_cs = 2.f * s12 + C2;
                float csv = num_cs * __frcp_rn(denom);
                float ssv = csv * (2.f * mu1 * mu2 + C1) *
                            __frcp_rn(mu1 * mu1 + mu2 * mu2 + C1);
                csSum   += csv;
                ssimSum += ssv;
            }
        }
    }

    #pragma unroll
    for (int off = 32; off > 0; off >>= 1) {
        csSum   += __shfl_down(csSum, off, 64);
        ssimSum += __shfl_down(ssimSum, off, 64);
    }
    int wave = tid >> 6, lane = tid & 63;
    if (lane == 0) {
        red[wave]     = csSum;
        red[8 + wave] = ssimSum;
    }
    __syncthreads();
    if (tid == 0) {
        float c = 0.f, s = 0.f;
        #pragma unroll
        for (int i = 0; i < 4; ++i) { c += red[i]; s += red[8 + i]; }
        int slot = (z * gridDim.y + blockIdx.y) * gridDim.x + blockIdx.x;
        partial[slot] = make_float2(c, s);
    }

    if (FUSE && tid < 128) {
        const int OH2 = H >> 1, OW2 = W >> 1;
        const int img = tid >> 6;
        const int rem = tid & 63;
        const int pr  = rem >> 2;
        const int pq  = rem & 3;
        const float* src = img ? b : a;
        float* dst = (img ? poolB : poolA) + (size_t)z * OH2 * OW2;
        size_t base = (size_t)(gy0 + 2 * pr) * W + gx0 + pq * 8;
        float4 r0 = *(const float4*)(src + base);
        float4 r1 = *(const float4*)(src + base + 4);
        float4 r2 = *(const float4*)(src + base + W);
        float4 r3 = *(const float4*)(src + base + W + 4);
        float4 o;
        o.x = 0.25f * (r0.x + r0.y + r2.x + r2.y);
        o.y = 0.25f * (r0.z + r0.w + r2.z + r2.w);
        o.z = 0.25f * (r1.x + r1.y + r3.x + r3.y);
        o.w = 0.25f * (r1.z + r1.w + r3.z + r3.w);
        *(float4*)(dst + (size_t)((gy0 >> 1) + pr) * OW2 + (gx0 >> 1) + pq * 4) = o;
    }
}

// ---------------------------------------------------------------------------
// Reduce all per-block partials (5 segments) and combine.
__global__ void final_kernel(const float2* __restrict__ partial, float* __restrict__ out) {
    __shared__ double red[8];
    __shared__ double resC[5], resS[5];
    const int segs[6] = {0, 12288, 15360, 16128, 16320, 16368};
    const int tid = threadIdx.x;
    for (int s = 0; s < 5; ++s) {
        double c = 0.0, v = 0.0;
        for (int i = segs[s] + tid; i < segs[s + 1]; i += 256) {
            float2 p = partial[i];
            c += (double)p.x;
            v += (double)p.y;
        }
        #pragma unroll
        for (int off = 32; off > 0; off >>= 1) {
            c += __shfl_down(c, off, 64);
            v += __shfl_down(v, off, 64);
        }
        int wave = tid >> 6, lane = tid & 63;
        __syncthreads();
        if (lane == 0) { red[wave] = c; red[4 + wave] = v; }
        __syncthreads();
        if (tid == 0) {
            resC[s] = red[0] + red[1] + red[2] + red[3];
            resS[s] = red[4] + red[5] + red[6] + red[7];
        }
    }
    __syncthreads();
    if (tid == 0) {
        const double wgt[5] = {0.0448, 0.2856, 0.3001, 0.2363, 0.1333};
        double ms = 1.0;
        for (int s = 0; s < 5; ++s) {
            int Hs = 512 >> s;
            double cnt = (double)NIMG * (double)(Hs - 10) * (double)(Hs - 10);
            double cs = resC[s] / cnt;
            double sv = resS[s] / cnt;
            if (cs < 0.0) cs = 0.0;
            if (sv < 0.0) sv = 0.0;
            cs = (cs + 1.0) * 0.5;
            sv = (sv + 1.0) * 0.5;
            ms *= pow((s < 4) ? cs : sv, wgt[s]);
        }
        out[0] = (float)(1.0 - ms);
    }
}

// ---------------------------------------------------------------------------
extern "C" void kernel_launch(void* const* d_in, const int* in_sizes, int n_in,
                              void* d_out, int out_size, void* d_ws, size_t ws_size,
                              hipStream_t stream) {
    (void)in_sizes; (void)n_in; (void)out_size; (void)ws_size;
    const float* A0 = (const float*)d_in[0];
    const float* B0 = (const float*)d_in[1];
    float* out = (float*)d_out;

    char* ws = (char*)d_ws;
    float2* partial = (float2*)ws;             // 16368 float2 = 131 KB
    float* pyr = (float*)(ws + (1 << 18));     // 256 KB offset

    float* pa[5] = {nullptr, nullptr, nullptr, nullptr, nullptr};
    float* pb[5] = {nullptr, nullptr, nullptr, nullptr, nullptr};
    size_t off = 0;
    for (int s = 1; s <= 4; ++s) {
        int Hs = 512 >> s;
        size_t n = (size_t)NIMG * Hs * Hs;
        pa[s] = pyr + off; off += n;
        pb[s] = pyr + off; off += n;
    }

    const int segs[5] = {0, 12288, 15360, 16128, 16320};

    const float* curA = A0;
    const float* curB = B0;
    for (int s = 0; s < 5; ++s) {
        int Hs = 512 >> s;
        int g  = Hs >> 5;                      // tiles exactly cover image
        dim3 grid(g, g, NIMG);
        if (s < 2) {
            ssim_mfma_kernel<true><<<grid, 256, 0, stream>>>(
                curA, curB, Hs, Hs, partial + segs[s], pa[s + 1], pb[s + 1]);
            curA = pa[s + 1];
            curB = pb[s + 1];
        } else if (s < 4) {
            ssim_scalar_kernel<true><<<grid, 256, 0, stream>>>(
                curA, curB, Hs, Hs, partial + segs[s], pa[s + 1], pb[s + 1]);
            curA = pa[s + 1];
            curB = pb[s + 1];
        } else {
            ssim_scalar_kernel<false><<<grid, 256, 0, stream>>>(
                curA, curB, Hs, Hs, partial + segs[s], nullptr, nullptr);
        }
    }

    final_kernel<<<1, 256, 0, stream>>>(partial, out);
}

// Round 9
// 214.847 us; speedup vs baseline: 2.6429x; 1.1302x over previous
//
#include <hip/hip_runtime.h>

#define HALO 10
#define NIMG 48                 // 16 batch * 3 channels

// Gaussian(sigma=1.5, 11 taps), normalized (computed offline in double).
#define GWLIST { 0.0010284f, 0.0075987f, 0.0360008f, 0.1093607f, 0.2130056f, \
                 0.2660117f, 0.2130056f, 0.1093607f, 0.0360008f, 0.0075987f, 0.0010284f }

// ======================= MFMA kernel (scales 0,1) ==========================
// fp16 pitches padded to 56 halves (112 B -> bank-stride 28, gcd(28,32)=4 ->
// 2-way aliasing = free; R8's pitch 48/96B gave 4-way conflicts, 4.4M cycles).
#define PP   56                 // stage-1 plane pitch (fp16 units)
#define PSZ  (48 * 56)          // plane size = 2688 fp16
#define HTP  56                 // h_T pitch along r (fp16 units)
#define HTSZ (32 * 56)          // per-quantity h_T = 1792 fp16
#define WT0  (5 * PSZ)          // wfrag table offset = 13440
#define LDSH (WT0 + 64 * 8)     // 13952 fp16 = 27904 B

typedef _Float16 half8 __attribute__((ext_vector_type(8)));
typedef _Float16 half4 __attribute__((ext_vector_type(4)));
typedef float    floatx4 __attribute__((ext_vector_type(4)));

// Per 32x32-output block:
//  stage 1: load 48x48 region, build 5 fp16 quantity planes in LDS
//           (squares/products in packed fp16 from the quantized signal)
//  stage 2: h-conv via mfma_f32_16x16x32_f16; C kept in REGISTERS,
//           extra barrier, then written as fp16 h_T transposed into the
//           (dead) plane region -> LDS 27.9 KB -> 5 blocks/CU
//  stage 3: v-conv via mfma, SSIM on C fragments, block reduce
//           (+ fused 2x2 avg-pool).
// Weight band fragment w[(lane>>4)*8 + i - (lane&15)] is computed by wave 0
// once into a 64-entry LDS table (was 176 VALU ops in EVERY thread).
// fp16 only for scales 0-1 (cs denominators >= 0.04); deeper scales use the
// exact fp32 scalar kernel (R7 failed at 9.8e-3 with all scales fp16).
template <bool FUSE>
__global__ __launch_bounds__(256, 5) void ssim_mfma_kernel(
    const float* __restrict__ A, const float* __restrict__ B,
    int H, int W, float2* __restrict__ partial,
    float* __restrict__ poolA, float* __restrict__ poolB)
{
    __shared__ __align__(16) _Float16 sm[LDSH];   // 27904 B
    __shared__ float red[16];

    const float w[11] = GWLIST;
    const int tid  = threadIdx.x;
    const int lane = tid & 63;
    const int wv   = tid >> 6;
    const int gx0  = blockIdx.x * 32;
    const int gy0  = blockIdx.y * 32;
    const int z    = blockIdx.z;
    const float* a = A + (size_t)z * H * W;
    const float* b = B + (size_t)z * H * W;

    // ---- wave 0: build band-weight fragment table (64 lanes x half8) ----
    if (tid < 64) {
        int base = ((tid >> 4) << 3) - (tid & 15);
        half8 wf;
        #pragma unroll
        for (int i = 0; i < 8; ++i) {
            int j = base + i;
            float v = 0.f;
            #pragma unroll
            for (int J = 0; J < 11; ++J) v = (j == J) ? w[J] : v;
            wf[i] = (_Float16)v;
        }
        *(half8*)&sm[WT0 + tid * 8] = wf;
    }

    // ---- stage 1: 48x48 region -> 5 fp16 quantity planes ----------------
    const bool fast = (gy0 + 48 <= H) && (gx0 + 48 <= W);
    for (int e = tid; e < 288; e += 256) {        // 48 rows x 6 col-octets
        int r = e / 6, c8 = e - r * 6;
        float fa[8], fb[8];
        if (fast) {
            const float* pa = a + (size_t)(gy0 + r) * W + gx0 + c8 * 8;
            const float* pb = b + (size_t)(gy0 + r) * W + gx0 + c8 * 8;
            *(float4*)&fa[0] = *(const float4*)pa;
            *(float4*)&fa[4] = *(const float4*)(pa + 4);
            *(float4*)&fb[0] = *(const float4*)pb;
            *(float4*)&fb[4] = *(const float4*)(pb + 4);
        } else {
            int gy = gy0 + r;
            #pragma unroll
            for (int i = 0; i < 8; ++i) {
                int gx = gx0 + c8 * 8 + i;
                bool ok = (gy < H) && (gx < W);
                size_t idx = (size_t)gy * W + gx;
                fa[i] = ok ? a[idx] : 0.f;
                fb[i] = ok ? b[idx] : 0.f;
            }
        }
        half8 ha, hb;
        #pragma unroll
        for (int i = 0; i < 8; ++i) {
            ha[i] = (_Float16)fa[i];
            hb[i] = (_Float16)fb[i];
        }
        half8 haa = ha * ha;      // v_pk_mul_f16; == fp16(fp32(qa*qa))
        half8 hbb = hb * hb;
        half8 hab = ha * hb;
        int o = r * PP + c8 * 8;
        *(half8*)&sm[o + 0 * PSZ] = ha;
        *(half8*)&sm[o + 1 * PSZ] = hb;
        *(half8*)&sm[o + 2 * PSZ] = haa;
        *(half8*)&sm[o + 3 * PSZ] = hbb;
        *(half8*)&sm[o + 4 * PSZ] = hab;
    }
    __syncthreads();

    // ---- fetch band-weight fragment (one b128 per thread) ---------------
    const half8 wfrag = *(const half8*)&sm[WT0 + lane * 8];

    // ---- stage 2a: h-conv via MFMA, results held in registers -----------
    // job jj -> (q, m0 in {0,16,32}, x0 in {0,16}); 30 jobs over 4 waves.
    half4 res[8];
    {
        const int arow = (lane & 15) * PP + ((lane >> 4) << 3);
        #pragma unroll
        for (int u = 0; u < 8; ++u) {
            int jj = wv + 4 * u;
            if (jj < 30) {                        // wave-uniform
                int q = jj / 6, rem = jj - q * 6;
                int m0 = (rem >> 1) << 4;
                int x0 = (rem & 1) << 4;
                half8 afrag = *(const half8*)&sm[q * PSZ + m0 * PP + x0 + arow];
                floatx4 c = {0.f, 0.f, 0.f, 0.f};
                c = __builtin_amdgcn_mfma_f32_16x16x32_f16(afrag, wfrag, c, 0, 0, 0);
                half4 hv;
                hv[0] = (_Float16)c[0]; hv[1] = (_Float16)c[1];
                hv[2] = (_Float16)c[2]; hv[3] = (_Float16)c[3];
                res[u] = hv;
            }
        }
    }
    __syncthreads();      // all plane reads done; plane region now reusable

    // ---- stage 2b: write transposed fp16 h_T into (dead) plane region ---
    {
        const int crow = (lane & 15) * HTP + ((lane >> 4) << 2);
        #pragma unroll
        for (int u = 0; u < 8; ++u) {
            int jj = wv + 4 * u;
            if (jj < 30) {
                int q = jj / 6, rem = jj - q * 6;
                int m0 = (rem >> 1) << 4;
                int x0 = (rem & 1) << 4;
                *(half4*)&sm[q * HTSZ + x0 * HTP + m0 + crow] = res[u];
            }
        }
    }
    __syncthreads();

    // ---- stage 3: v-conv via MFMA (one 16x16 subtile per wave) + SSIM ---
    float csSum = 0.f, ssimSum = 0.f;
    {
        const int y0 = (wv >> 1) << 4;
        const int x0 = (wv & 1) << 4;
        const int brow = (lane & 15) * HTP + ((lane >> 4) << 3);
        floatx4 m[5];
        #pragma unroll
        for (int q = 0; q < 5; ++q) {
            half8 bfrag = *(const half8*)&sm[q * HTSZ + x0 * HTP + y0 + brow];
            floatx4 c = {0.f, 0.f, 0.f, 0.f};
            m[q] = __builtin_amdgcn_mfma_f32_16x16x32_f16(wfrag, bfrag, c, 0, 0, 0);
        }
        const int OH = H - HALO, OW = W - HALO;
        const int gx  = gx0 + x0 + (lane & 15);
        const int gyb = gy0 + y0 + ((lane >> 4) << 2);
        const float C1 = 1e-4f;   // (0.01*1)^2
        const float C2 = 9e-4f;   // (0.03*1)^2
        if (gx < OW) {
            #pragma unroll
            for (int i = 0; i < 4; ++i) {
                int gy = gyb + i;
                if (gy < OH) {
                    float mu1 = m[0][i], mu2 = m[1][i];
                    float s1sq = m[2][i] - mu1 * mu1;
                    float s2sq = m[3][i] - mu2 * mu2;
                    float s12  = m[4][i] - mu1 * mu2;
                    float denom = s1sq + s2sq + C2;
                    float num   = 2.f * s12 + C2;
                    float csv = num * __frcp_rn(denom);
                    float ssv = csv * (2.f * mu1 * mu2 + C1) *
                                __frcp_rn(mu1 * mu1 + mu2 * mu2 + C1);
                    csSum   += csv;
                    ssimSum += ssv;
                }
            }
        }
    }

    // ---- block reduction -> per-block partial slot ----------------------
    #pragma unroll
    for (int off = 32; off > 0; off >>= 1) {
        csSum   += __shfl_down(csSum, off, 64);
        ssimSum += __shfl_down(ssimSum, off, 64);
    }
    if (lane == 0) {
        red[wv]     = csSum;
        red[8 + wv] = ssimSum;
    }
    __syncthreads();
    if (tid == 0) {
        float c = 0.f, s = 0.f;
        #pragma unroll
        for (int i = 0; i < 4; ++i) { c += red[i]; s += red[8 + i]; }
        int slot = (z * gridDim.y + blockIdx.y) * gridDim.x + blockIdx.x;
        partial[slot] = make_float2(c, s);
    }

    // ---- fused 2x2 avg-pool of this block's own 32x32 input region ------
    if (FUSE && tid < 128) {
        const int OH2 = H >> 1, OW2 = W >> 1;
        const int img = tid >> 6;            // 0 = A, 1 = B
        const int rem = tid & 63;
        const int pr  = rem >> 2;            // pooled row 0..15
        const int pq  = rem & 3;             // pooled float4-col 0..3
        const float* src = img ? b : a;
        float* dst = (img ? poolB : poolA) + (size_t)z * OH2 * OW2;
        size_t base = (size_t)(gy0 + 2 * pr) * W + gx0 + pq * 8;
        float4 r0 = *(const float4*)(src + base);
        float4 r1 = *(const float4*)(src + base + 4);
        float4 r2 = *(const float4*)(src + base + W);
        float4 r3 = *(const float4*)(src + base + W + 4);
        float4 o;
        o.x = 0.25f * (r0.x + r0.y + r2.x + r2.y);
        o.y = 0.25f * (r0.z + r0.w + r2.z + r2.w);
        o.z = 0.25f * (r1.x + r1.y + r3.x + r3.y);
        o.w = 0.25f * (r1.z + r1.w + r3.z + r3.w);
        *(float4*)(dst + (size_t)((gy0 >> 1) + pr) * OW2 + (gx0 >> 1) + pq * 4) = o;
    }
}

// ================= exact fp32 scalar kernel (scales 2-4) ===================
#define TH   32
#define ROWS (TH + HALO)      // 42
#define HSTR 32
#define HQ   (ROWS * HSTR)    // 1344 floats

template <bool FUSE>
__global__ __launch_bounds__(256, 5) void ssim_scalar_kernel(
    const float* __restrict__ A, const float* __restrict__ B,
    int H, int W, float2* __restrict__ partial,
    float* __restrict__ poolA, float* __restrict__ poolB)
{
    __shared__ __align__(16) float lds[5 * HQ];   // 26880 B
    __shared__ float red[16];

    const float w[11] = GWLIST;

    const int tid = threadIdx.x;
    const int gx0 = blockIdx.x * 32;
    const int gy0 = blockIdx.y * TH;
    const int z   = blockIdx.z;
    const float* a = A + (size_t)z * H * W;
    const float* b = B + (size_t)z * H * W;

    const bool fast = (gy0 + ROWS <= H) && (gx0 + 44 <= W);
    for (int e = tid; e < ROWS * 8; e += 256) {
        int r = e >> 3, c0 = (e & 7) * 4;
        int gy = gy0 + r;
        float s1[4]  = {0.f, 0.f, 0.f, 0.f};
        float s2[4]  = {0.f, 0.f, 0.f, 0.f};
        float s11[4] = {0.f, 0.f, 0.f, 0.f};
        float s22[4] = {0.f, 0.f, 0.f, 0.f};
        float s12[4] = {0.f, 0.f, 0.f, 0.f};
        #pragma unroll
        for (int c = 0; c < 4; ++c) {
            float ea[4], eb[4];
            if (fast) {
                const float* pa = a + (size_t)gy * W + gx0 + c0 + 4 * c;
                const float* pb = b + (size_t)gy * W + gx0 + c0 + 4 * c;
                *(float4*)&ea[0] = *(const float4*)pa;
                *(float4*)&eb[0] = *(const float4*)pb;
            } else {
                #pragma unroll
                for (int t = 0; t < 4; ++t) {
                    int gx = gx0 + c0 + 4 * c + t;
                    bool ok = (gy < H) && (gx < W);
                    size_t idx = (size_t)gy * W + gx;
                    ea[t] = ok ? a[idx] : 0.f;
                    eb[t] = ok ? b[idx] : 0.f;
                }
            }
            #pragma unroll
            for (int mm = 0; mm < 4; ++mm) {
                const int i = 4 * c + mm;
                float va = ea[mm], vb = eb[mm];
                float vaa = va * va, vbb = vb * vb, vab = va * vb;
                #pragma unroll
                for (int k = 0; k < 4; ++k) {
                    const int j = i - k;
                    if (j >= 0 && j <= 10) {
                        float wj = w[j];
                        s1[k]  += wj * va;
                        s2[k]  += wj * vb;
                        s11[k] += wj * vaa;
                        s22[k] += wj * vbb;
                        s12[k] += wj * vab;
                    }
                }
            }
        }
        int hb = r * HSTR + c0;
        *(float4*)&lds[hb + 0 * HQ] = make_float4(s1[0],  s1[1],  s1[2],  s1[3]);
        *(float4*)&lds[hb + 1 * HQ] = make_float4(s2[0],  s2[1],  s2[2],  s2[3]);
        *(float4*)&lds[hb + 2 * HQ] = make_float4(s11[0], s11[1], s11[2], s11[3]);
        *(float4*)&lds[hb + 3 * HQ] = make_float4(s22[0], s22[1], s22[2], s22[3]);
        *(float4*)&lds[hb + 4 * HQ] = make_float4(s12[0], s12[1], s12[2], s12[3]);
    }
    __syncthreads();

    const float C1 = 1e-4f;
    const float C2 = 9e-4f;
    float csSum = 0.f, ssimSum = 0.f;
    {
        const int ox  = tid & 31;
        const int oy0 = (tid >> 5) * 4;
        float m[5][4];
        #pragma unroll
        for (int q = 0; q < 5; ++q) {
            const float* hq = &lds[q * HQ + oy0 * HSTR + ox];
            float win[14];
            #pragma unroll
            for (int i = 0; i < 14; ++i) win[i] = hq[i * HSTR];
            #pragma unroll
            for (int k = 0; k < 4; ++k) {
                float acc = 0.f;
                #pragma unroll
                for (int j = 0; j < 11; ++j) acc += w[j] * win[k + j];
                m[q][k] = acc;
            }
        }
        const int OH = H - HALO, OW = W - HALO;
        const int gx = gx0 + ox;
        #pragma unroll
        for (int k = 0; k < 4; ++k) {
            int gy = gy0 + oy0 + k;
            if (gy < OH && gx < OW) {
                float mu1 = m[0][k], mu2 = m[1][k];
                float s1sq = m[2][k] - mu1 * mu1;
                float s2sq = m[3][k] - mu2 * mu2;
                float s12  = m[4][k] - mu1 * mu2;
                float denom  = s1sq + s2sq + C2;
                float num_cs = 2.f * s12 + C2;
                float csv = num_cs * __frcp_rn(denom);
                float ssv = csv * (2.f * mu1 * mu2 + C1) *
                            __frcp_rn(mu1 * mu1 + mu2 * mu2 + C1);
                csSum   += csv;
                ssimSum += ssv;
            }
        }
    }

    #pragma unroll
    for (int off = 32; off > 0; off >>= 1) {
        csSum   += __shfl_down(csSum, off, 64);
        ssimSum += __shfl_down(ssimSum, off, 64);
    }
    int wave = tid >> 6, lane = tid & 63;
    if (lane == 0) {
        red[wave]     = csSum;
        red[8 + wave] = ssimSum;
    }
    __syncthreads();
    if (tid == 0) {
        float c = 0.f, s = 0.f;
        #pragma unroll
        for (int i = 0; i < 4; ++i) { c += red[i]; s += red[8 + i]; }
        int slot = (z * gridDim.y + blockIdx.y) * gridDim.x + blockIdx.x;
        partial[slot] = make_float2(c, s);
    }

    if (FUSE && tid < 128) {
        const int OH2 = H >> 1, OW2 = W >> 1;
        const int img = tid >> 6;
        const int rem = tid & 63;
        const int pr  = rem >> 2;
        const int pq  = rem & 3;
        const float* src = img ? b : a;
        float* dst = (img ? poolB : poolA) + (size_t)z * OH2 * OW2;
        size_t base = (size_t)(gy0 + 2 * pr) * W + gx0 + pq * 8;
        float4 r0 = *(const float4*)(src + base);
        float4 r1 = *(const float4*)(src + base + 4);
        float4 r2 = *(const float4*)(src + base + W);
        float4 r3 = *(const float4*)(src + base + W + 4);
        float4 o;
        o.x = 0.25f * (r0.x + r0.y + r2.x + r2.y);
        o.y = 0.25f * (r0.z + r0.w + r2.z + r2.w);
        o.z = 0.25f * (r1.x + r1.y + r3.x + r3.y);
        o.w = 0.25f * (r1.z + r1.w + r3.z + r3.w);
        *(float4*)(dst + (size_t)((gy0 >> 1) + pr) * OW2 + (gx0 >> 1) + pq * 4) = o;
    }
}

// ---------------------------------------------------------------------------
// Reduce all per-block partials (5 segments) and combine.
__global__ void final_kernel(const float2* __restrict__ partial, float* __restrict__ out) {
    __shared__ double red[8];
    __shared__ double resC[5], resS[5];
    const int segs[6] = {0, 12288, 15360, 16128, 16320, 16368};
    const int tid = threadIdx.x;
    for (int s = 0; s < 5; ++s) {
        double c = 0.0, v = 0.0;
        #pragma unroll 4
        for (int i = segs[s] + tid; i < segs[s + 1]; i += 256) {
            float2 p = partial[i];
            c += (double)p.x;
            v += (double)p.y;
        }
        #pragma unroll
        for (int off = 32; off > 0; off >>= 1) {
            c += __shfl_down(c, off, 64);
            v += __shfl_down(v, off, 64);
        }
        int wave = tid >> 6, lane = tid & 63;
        __syncthreads();
        if (lane == 0) { red[wave] = c; red[4 + wave] = v; }
        __syncthreads();
        if (tid == 0) {
            resC[s] = red[0] + red[1] + red[2] + red[3];
            resS[s] = red[4] + red[5] + red[6] + red[7];
        }
    }
    __syncthreads();
    if (tid == 0) {
        const double wgt[5] = {0.0448, 0.2856, 0.3001, 0.2363, 0.1333};
        double ms = 1.0;
        for (int s = 0; s < 5; ++s) {
            int Hs = 512 >> s;
            double cnt = (double)NIMG * (double)(Hs - 10) * (double)(Hs - 10);
            double cs = resC[s] / cnt;
            double sv = resS[s] / cnt;
            if (cs < 0.0) cs = 0.0;
            if (sv < 0.0) sv = 0.0;
            cs = (cs + 1.0) * 0.5;
            sv = (sv + 1.0) * 0.5;
            ms *= pow((s < 4) ? cs : sv, wgt[s]);
        }
        out[0] = (float)(1.0 - ms);
    }
}

// ---------------------------------------------------------------------------
extern "C" void kernel_launch(void* const* d_in, const int* in_sizes, int n_in,
                              void* d_out, int out_size, void* d_ws, size_t ws_size,
                              hipStream_t stream) {
    (void)in_sizes; (void)n_in; (void)out_size; (void)ws_size;
    const float* A0 = (const float*)d_in[0];
    const float* B0 = (const float*)d_in[1];
    float* out = (float*)d_out;

    char* ws = (char*)d_ws;
    float2* partial = (float2*)ws;             // 16368 float2 = 131 KB
    float* pyr = (float*)(ws + (1 << 18));     // 256 KB offset

    float* pa[5] = {nullptr, nullptr, nullptr, nullptr, nullptr};
    float* pb[5] = {nullptr, nullptr, nullptr, nullptr, nullptr};
    size_t off = 0;
    for (int s = 1; s <= 4; ++s) {
        int Hs = 512 >> s;
        size_t n = (size_t)NIMG * Hs * Hs;
        pa[s] = pyr + off; off += n;
        pb[s] = pyr + off; off += n;
    }

    const int segs[5] = {0, 12288, 15360, 16128, 16320};

    const float* curA = A0;
    const float* curB = B0;
    for (int s = 0; s < 5; ++s) {
        int Hs = 512 >> s;
        int g  = Hs >> 5;                      // tiles exactly cover image
        dim3 grid(g, g, NIMG);
        if (s < 2) {
            ssim_mfma_kernel<true><<<grid, 256, 0, stream>>>(
                curA, curB, Hs, Hs, partial + segs[s], pa[s + 1], pb[s + 1]);
            curA = pa[s + 1];
            curB = pb[s + 1];
        } else if (s < 4) {
            ssim_scalar_kernel<true><<<grid, 256, 0, stream>>>(
                curA, curB, Hs, Hs, partial + segs[s], pa[s + 1], pb[s + 1]);
            curA = pa[s + 1];
            curB = pb[s + 1];
        } else {
            ssim_scalar_kernel<false><<<grid, 256, 0, stream>>>(
                curA, curB, Hs, Hs, partial + segs[s], nullptr, nullptr);
        }
    }

    final_kernel<<<1, 256, 0, stream>>>(partial, out);
}